// Round 16
// baseline (518.571 us; speedup 1.0000x reference)
//
#include <hip/hip_runtime.h>
#include <hip/hip_bf16.h>
#include <math.h>

// ---------------------------------------------------------------------------
// Hypergraph kNN, fp32-faithful to a numpy float32 reference:
//   eud[i,j] = sqrt( np.sum( (f[i]-f[j])**2 ) )   (DIRECT form, verified r6)
//   distances = adj/np.sum(adj,1) + eud/np.sum(eud,1);  top-9 per row.
// Phase 1: split-bf16 MFMA GEMM (triangular, r14) -> u16 eud + numpy-ordered
//   fp32 leaf sums; rowsel (r16): exact-numpy Sa + Se tree, then
//   THRESHOLD-COMPACT selection — tau = 16th-largest of 256 per-thread
//   maxima (provably <= true 16th-best score), compact all >= tau
//   (provably <= 512 items), 16 exact argmax extractions -> the identical
//   approx-top-16 set the old INS-chain path produced (bit-same output).
// Phase 2: wave-cooperative exact re-score of approx-top-16 (r13/r15).
// ---------------------------------------------------------------------------

typedef short bf16x8 __attribute__((ext_vector_type(8)));   // 8 bf16 (4 VGPR)
typedef float f32x4 __attribute__((ext_vector_type(4)));

__device__ __forceinline__ float fbar(float x) {  // block FMA contraction
  asm volatile("" : "+v"(x));
  return x;
}
__device__ __forceinline__ unsigned short f2bf(float x) {  // RNE
  union { float f; unsigned u; } v; v.f = x;
  unsigned r = (v.u + 0x7fffu + ((v.u >> 16) & 1u)) >> 16;
  return (unsigned short)r;
}
__device__ __forceinline__ float bf2f(unsigned short b) {
  union { unsigned u; float f; } v; v.u = ((unsigned)b) << 16; return v.f;
}

// ---- split f32 -> hi/lo bf16 planes ---------------------------------------
__global__ __launch_bounds__(256) void knn_cvt(const float* __restrict__ f,
                                               unsigned short* __restrict__ hi,
                                               unsigned short* __restrict__ lo,
                                               int n4) {
  int i = blockIdx.x * 256 + threadIdx.x;
  if (i >= n4) return;
  float4 v = ((const float4*)f)[i];
  ushort4 h, l;
  h.x = f2bf(v.x); l.x = f2bf(v.x - bf2f(h.x));
  h.y = f2bf(v.y); l.y = f2bf(v.y - bf2f(h.y));
  h.z = f2bf(v.z); l.z = f2bf(v.z - bf2f(h.z));
  h.w = f2bf(v.w); l.w = f2bf(v.w - bf2f(h.w));
  ((ushort4*)hi)[i] = h;
  ((ushort4*)lo)[i] = l;
}

// ---- sq_norms: np.sum(f*f, axis=1) in exact numpy fp32 pairwise order -----
__global__ __launch_bounds__(128) void knn_sqn_np(const float* __restrict__ f,
                                                  float* __restrict__ sqn32,
                                                  int N, int D) {
  int row = blockIdx.x;             // D == 512: 4 leaves of 128
  int t = threadIdx.x;              // 128 threads
  __shared__ float a[512];
  __shared__ float R[4][8];
  const float* fr = f + (size_t)row * D;
  float4 v = ((const float4*)fr)[t];
  a[t * 4 + 0] = v.x * v.x;
  a[t * 4 + 1] = v.y * v.y;
  a[t * 4 + 2] = v.z * v.z;
  a[t * 4 + 3] = v.w * v.w;
  __syncthreads();
  if (t < 32) {
    int lf = t >> 3, m = t & 7;
    float s = a[lf * 128 + m];
    for (int g = 1; g < 16; ++g) s += a[lf * 128 + 8 * g + m];
    R[lf][m] = s;
  }
  __syncthreads();
  if (t == 0) {
    float L[4];
#pragma unroll
    for (int lf = 0; lf < 4; ++lf)
      L[lf] = ((R[lf][0] + R[lf][1]) + (R[lf][2] + R[lf][3])) +
              ((R[lf][4] + R[lf][5]) + (R[lf][6] + R[lf][7]));
    sqn32[row] = (L[0] + L[1]) + (L[2] + L[3]);
  }
}

// ---- split-bf16 MFMA GEMM: 128x128 tile, 4 waves, BK=32, TRIANGULAR -------
#define TBM 128
#define TBN 128
#define TBK 32
__global__ __launch_bounds__(256) void knn_gemm_mfma(
    const unsigned short* __restrict__ fhi, const unsigned short* __restrict__ flo,
    const float* __restrict__ sqn32, unsigned short* __restrict__ eud,
    float* __restrict__ leaf, int N, int D) {
  // aliased LDS: staging (4 x 10240B) in k-loop; epilogue: Et[64][132] (33792)
  // + R2[64][8] (@33792) + R3[128][8] (@35840, persists across passes)
  __shared__ __align__(16) char smem[40960];
  unsigned short (*Ah)[40] = (unsigned short(*)[40])(smem);
  unsigned short (*Al)[40] = (unsigned short(*)[40])(smem + 10240);
  unsigned short (*Bh)[40] = (unsigned short(*)[40])(smem + 20480);
  unsigned short (*Bl)[40] = (unsigned short(*)[40])(smem + 30720);

  int tid = threadIdx.x;

  // triangular decode: block -> (by <= bx)
  int NT = N / TBM;
  int b = blockIdx.x;
  int by = 0, rem = NT;
  while (b >= rem) { b -= rem; ++by; --rem; }
  int bx = by + b;

  int i0 = by * TBM, j0 = bx * TBN;
  int wid = tid >> 6, l = tid & 63;
  int wr = wid >> 1, wc = wid & 1;  // wave -> 64x64 quadrant
  int lr = l & 15, lk = l >> 4;     // frag row, k-chunk

  f32x4 acc[4][4] = {};             // statically indexed only (unrolled)

  int sr = tid >> 1;                // staging row 0..127
  int sh = (tid & 1) << 4;          // k-half 0/16

  for (int k0 = 0; k0 < D; k0 += TBK) {
    size_t aoff = (size_t)(i0 + sr) * D + k0 + sh;
    size_t boff = (size_t)(j0 + sr) * D + k0 + sh;
    *(uint4*)&Ah[sr][sh]     = *(const uint4*)(fhi + aoff);
    *(uint4*)&Ah[sr][sh + 8] = *(const uint4*)(fhi + aoff + 8);
    *(uint4*)&Al[sr][sh]     = *(const uint4*)(flo + aoff);
    *(uint4*)&Al[sr][sh + 8] = *(const uint4*)(flo + aoff + 8);
    *(uint4*)&Bh[sr][sh]     = *(const uint4*)(fhi + boff);
    *(uint4*)&Bh[sr][sh + 8] = *(const uint4*)(fhi + boff + 8);
    *(uint4*)&Bl[sr][sh]     = *(const uint4*)(flo + boff);
    *(uint4*)&Bl[sr][sh + 8] = *(const uint4*)(flo + boff + 8);
    __syncthreads();

    bf16x8 ah[4], al_[4], bh[4], bl_[4];
#pragma unroll
    for (int fr = 0; fr < 4; ++fr) {
      ah[fr]  = *(const bf16x8*)&Ah[wr * 64 + fr * 16 + lr][lk * 8];
      al_[fr] = *(const bf16x8*)&Al[wr * 64 + fr * 16 + lr][lk * 8];
      bh[fr]  = *(const bf16x8*)&Bh[wc * 64 + fr * 16 + lr][lk * 8];
      bl_[fr] = *(const bf16x8*)&Bl[wc * 64 + fr * 16 + lr][lk * 8];
    }
#pragma unroll
    for (int fr = 0; fr < 4; ++fr)
#pragma unroll
      for (int fc = 0; fc < 4; ++fc) {
        acc[fr][fc] = __builtin_amdgcn_mfma_f32_16x16x32_bf16(
            ah[fr], bh[fc], acc[fr][fc], 0, 0, 0);
        acc[fr][fc] = __builtin_amdgcn_mfma_f32_16x16x32_bf16(
            ah[fr], bl_[fc], acc[fr][fc], 0, 0, 0);
        acc[fr][fc] = __builtin_amdgcn_mfma_f32_16x16x32_bf16(
            al_[fr], bh[fc], acc[fr][fc], 0, 0, 0);
      }
    __syncthreads();
  }

  // ---- epilogue ----
  float (*Et)[132] = (float(*)[132])(smem);          // 64 rows x 132 (padded)
  float (*R2)[8]   = (float(*)[8])(smem + 33792);    // standard chains
  float (*R3)[8]   = (float(*)[8])(smem + 35840);    // mirror chains (128x8)

  float sj[4];
#pragma unroll
  for (int fc = 0; fc < 4; ++fc) sj[fc] = sqn32[j0 + wc * 64 + fc * 16 + lr];

  bool mir = (bx != by);

#pragma unroll
  for (int pass = 0; pass < 2; ++pass) {
    if (wr == pass) {
#pragma unroll
      for (int fr = 0; fr < 4; ++fr) {
#pragma unroll
        for (int v = 0; v < 4; ++v) {
          int irow = fr * 16 + lk * 4 + v;          // 0..63 within pass half
          int i = i0 + pass * 64 + irow;
          float si = sqn32[i];
#pragma unroll
          for (int fc = 0; fc < 4; ++fc) {
            int jcol = wc * 64 + fc * 16 + lr;
            int j = j0 + jcol;
            float sq = si + sj[fc] - 2.0f * acc[fr][fc][v];
            float e = (sq > 0.0f && i != j) ? sqrtf(sq) : 0.0f;
            Et[irow][jcol] = e;
            int q = (int)(e * 1024.0f + 0.5f);
            if (q > 65535) q = 65535;
            eud[(size_t)i * N + j] = (unsigned short)q;
          }
        }
      }
    }
    __syncthreads();

    // standard numpy leaf chains: 64 rows x 8 accs, stride-8 ascending
#pragma unroll
    for (int u0 = 0; u0 < 2; ++u0) {
      int u = tid + u0 * 256;                       // 0..511
      int row = u >> 3, m = u & 7;
      float s = Et[row][m];
#pragma unroll
      for (int g = 1; g < 16; ++g) s += Et[row][8 * g + m];
      R2[row][m] = s;
    }

    if (mir) {
      // mirror partial chains: leaf elem idx = 64*pass + 8g + m over Et cols
#pragma unroll
      for (int u0 = 0; u0 < 4; ++u0) {
        int u = tid + u0 * 256;                     // 0..1023
        int jofs = u >> 3, m = u & 7;
        float s = (pass == 0) ? 0.0f : R3[jofs][m];
#pragma unroll
        for (int g = 0; g < 8; ++g) s += Et[8 * g + m][jofs];
        R3[jofs][m] = s;
      }
      // mirror eud write: eud[j][i-range], re-quantized from same floats
      {
        int j = tid >> 1, h = tid & 1;
        size_t base = (size_t)(j0 + j) * N + i0 + pass * 64 + h * 32;
        unsigned short buf[32];
#pragma unroll
        for (int ii = 0; ii < 32; ++ii) {
          float e = Et[h * 32 + ii][j];
          int q = (int)(e * 1024.0f + 0.5f);
          if (q > 65535) q = 65535;
          buf[ii] = (unsigned short)q;
        }
#pragma unroll
        for (int q4 = 0; q4 < 4; ++q4)
          *(uint4*)(eud + base + q4 * 8) = *(uint4*)&buf[q4 * 8];
      }
    }
    __syncthreads();

    if (tid < 64) {
      float v = ((R2[tid][0] + R2[tid][1]) + (R2[tid][2] + R2[tid][3])) +
                ((R2[tid][4] + R2[tid][5]) + (R2[tid][6] + R2[tid][7]));
      leaf[(size_t)(i0 + pass * 64 + tid) * 64 + bx] = v;
    }
    if (mir && pass == 1 && tid < 128) {
      float v = ((R3[tid][0] + R3[tid][1]) + (R3[tid][2] + R3[tid][3])) +
                ((R3[tid][4] + R3[tid][5]) + (R3[tid][6] + R3[tid][7]));
      leaf[(size_t)(j0 + tid) * 64 + by] = v;
    }
    __syncthreads();
  }
}

// ---- rowsel (r16): Sa + Se + threshold-compact approx-top-16 --------------
// tau = 16th-largest of 256 per-thread score maxima. The true top-16 lie in
// <=16 threads, so v16 >= m16 = tau (joint tie-removal only lowers tau —
// still safe). Elements >= tau live only in threads whose max >= tau
// -> count <= 16*32 = 512 (+fp32-tie slack; capacity 2048).
__global__ __launch_bounds__(256) void knn_rowsel(
    const float* __restrict__ adj, const unsigned short* __restrict__ eud,
    const float* __restrict__ leaf, int* __restrict__ cand,
    float* __restrict__ cansc,
    float* __restrict__ SaOut, float* __restrict__ SeOut, int N) {
  __shared__ float arow[8192];
  __shared__ float R[64][8];
  __shared__ float Lf[64];
  __shared__ float bc[2];
  __shared__ float maxv[256];
  __shared__ float tauS;
  __shared__ int   cnt;
  __shared__ float ls[2048];
  __shared__ int   lj[2048];

  int row = blockIdx.x;
  int t = threadIdx.x;
  const float* ar = adj + (size_t)row * N;

  // stage adjacency row (32 KB) once
#pragma unroll
  for (int c = 0; c < 8; ++c)
    ((float4*)arow)[c * 256 + t] = ((const float4*)ar)[c * 256 + t];
  if (t == 0) cnt = 0;
  __syncthreads();

  // Sa: numpy pairwise order — 64 leaves of 128, 8 stride-8 accumulators
  for (int u = t; u < 512; u += 256) {
    int lf = u >> 3, m = u & 7;
    float s = arow[lf * 128 + m];
    for (int g = 1; g < 16; ++g) s += arow[lf * 128 + 8 * g + m];
    R[lf][m] = s;
  }
  __syncthreads();
  if (t < 64)
    Lf[t] = ((R[t][0] + R[t][1]) + (R[t][2] + R[t][3])) +
            ((R[t][4] + R[t][5]) + (R[t][6] + R[t][7]));
  __syncthreads();
  for (int w = 32; w >= 1; w >>= 1) {
    if (t < w) Lf[t] = Lf[2 * t] + Lf[2 * t + 1];
    __syncthreads();
  }
  if (t == 0) { float Sa = Lf[0]; SaOut[row] = Sa; bc[0] = 1.0f / Sa; }
  __syncthreads();

  // Se: balanced tree over the 64 numpy-ordered gemm leaf sums
  if (t < 64) Lf[t] = leaf[(size_t)row * 64 + t];
  __syncthreads();
  for (int w = 32; w >= 1; w >>= 1) {
    if (t < w) Lf[t] = Lf[2 * t] + Lf[2 * t + 1];
    __syncthreads();
  }
  if (t == 0) {
    float Se = Lf[0]; SeOut[row] = Se;
    bc[1] = (float)(1.0 / ((double)Se * 1024.0));
  }
  __syncthreads();
  float ra = bc[0], re = bc[1];

  const unsigned short* er = eud + (size_t)row * N;

  // pass A: per-thread max of its 32 scores (identical expression to pass B)
  float mx = -3.0e38f;
#pragma unroll
  for (int it = 0; it < 8; ++it) {
    int j = it * 1024 + t * 4;
    float4 av = *(const float4*)(arow + j);
    ushort4 ev = *(const ushort4*)(er + j);
    mx = fmaxf(mx, av.x * ra + (float)ev.x * re);
    mx = fmaxf(mx, av.y * ra + (float)ev.y * re);
    mx = fmaxf(mx, av.z * ra + (float)ev.z * re);
    mx = fmaxf(mx, av.w * ra + (float)ev.w * re);
  }
  maxv[t] = mx;
  __syncthreads();

  // tau: 16th-largest distinct of the 256 maxima (wave 0)
  if (t < 64) {
    float a0 = maxv[t], a1 = maxv[t + 64], a2 = maxv[t + 128], a3 = maxv[t + 192];
#pragma unroll
    for (int r = 0; r < 16; ++r) {
      float lm = fmaxf(fmaxf(a0, a1), fmaxf(a2, a3));
      float cv = lm;
      for (int off = 32; off; off >>= 1) cv = fmaxf(cv, __shfl_xor(cv, off));
      if (r == 15 && t == 0) tauS = cv;
      if (a0 == cv) a0 = -3.0e38f;
      if (a1 == cv) a1 = -3.0e38f;
      if (a2 == cv) a2 = -3.0e38f;
      if (a3 == cv) a3 = -3.0e38f;
    }
  }
  __syncthreads();
  float tau = tauS;

  // pass B: compact all (score, j) with score >= tau
#pragma unroll
  for (int it = 0; it < 8; ++it) {
    int j = it * 1024 + t * 4;
    float4 av = *(const float4*)(arow + j);
    ushort4 ev = *(const ushort4*)(er + j);
    float s0 = av.x * ra + (float)ev.x * re;
    float s1 = av.y * ra + (float)ev.y * re;
    float s2 = av.z * ra + (float)ev.z * re;
    float s3 = av.w * ra + (float)ev.w * re;
    if (s0 >= tau) { int p = atomicAdd(&cnt, 1); if (p < 2048) { ls[p] = s0; lj[p] = j + 0; } }
    if (s1 >= tau) { int p = atomicAdd(&cnt, 1); if (p < 2048) { ls[p] = s1; lj[p] = j + 1; } }
    if (s2 >= tau) { int p = atomicAdd(&cnt, 1); if (p < 2048) { ls[p] = s2; lj[p] = j + 2; } }
    if (s3 >= tau) { int p = atomicAdd(&cnt, 1); if (p < 2048) { ls[p] = s3; lj[p] = j + 3; } }
  }
  __syncthreads();
  int C = cnt < 2048 ? cnt : 2048;

  // sentinels for slots 16..63 (distinct fake idx; never dereferenced)
  if (t >= 16 && t < 64) {
    cand[(size_t)row * 64 + t] = 0x40000000 + t;
    cansc[(size_t)row * 64 + t] = -3.0e38f;
  }

  // wave 0: 16 exact argmax extractions (score desc, index asc)
  if (t < 64) {
    for (int r = 0; r < 16; ++r) {
      float bv = -3.0e38f; int bj = 0x7fffffff; int bp = -1;
      for (int i = t; i < C; i += 64) {
        float v = ls[i]; int jj = lj[i];
        if (v > bv || (v == bv && jj < bj)) { bv = v; bj = jj; bp = i; }
      }
      for (int off = 32; off; off >>= 1) {
        float ov = __shfl_xor(bv, off);
        int oj = __shfl_xor(bj, off);
        int op = __shfl_xor(bp, off);
        if (ov > bv || (ov == bv && oj < bj)) { bv = ov; bj = oj; bp = op; }
      }
      if (t == 0) {
        cand[(size_t)row * 64 + r] = bj;
        cansc[(size_t)row * 64 + r] = bv;
        ls[bp] = -3.0e38f;                     // remove winner
      }
      asm volatile("s_waitcnt lgkmcnt(0)" ::: "memory");
      __builtin_amdgcn_sched_barrier(0);
    }
  }
}

// ---- phase 2 (r15): wave-cooperative exact re-score of approx-top-16 ------
// [4][136] LDS padding: chain reads hit distinct banks. Final top-9 via
// wave-0 register shfl-argmax (exact same total order).
__global__ __launch_bounds__(256) void knn_refine(
    const float* __restrict__ f, const float* __restrict__ adj,
    const float* __restrict__ Sa, const float* __restrict__ Se,
    const int* __restrict__ cand, const float* __restrict__ cansc,
    float* __restrict__ out, int N, int D, int KP1) {
  int row = blockIdx.x;
  int t = threadIdx.x;
  int wave = t >> 6, lane = t & 63;

  __shared__ float fis[4][136];
  __shared__ float fjs[4][2][4][136];
  __shared__ float sval[64];
  __shared__ float asc[64];
  __shared__ int   ajx[64];
  __shared__ int   gidx[16];

  if (t < 64) {
    ajx[t] = cand[(size_t)row * 64 + t];
    asc[t] = cansc[(size_t)row * 64 + t];
    sval[t] = -3.0e38f;
  }
  if (t < 128) {
    int e0 = t * 4;
    *(float4*)&fis[e0 >> 7][e0 & 127] =
        ((const float4*)(f + (size_t)row * D))[t];
  }
  __syncthreads();

  // approx rank among the 64 (tie-break: lower index ranks higher)
  if (t < 64) {
    int myj = ajx[t]; float mys = asc[t];
    int rank = 0;
    for (int c = 0; c < 64; ++c) {
      float v = asc[c]; int jc = ajx[c];
      if (v > mys || (v == mys && jc < myj)) ++rank;
    }
    if (rank < 16) gidx[rank] = t;
  }
  __syncthreads();

  float sa = Sa[row], se = Se[row];
  int h = lane >> 5;        // half 0/1 within wave
  int hl = lane & 31;       // lane in half
  int lf = hl >> 3, m = hl & 7;

#pragma unroll
  for (int p = 0; p < 2; ++p) {
    int slot = wave * 4 + p * 2 + h;        // rank slot handled by this half
    int c = gidx[slot];
    int j = ajx[c];

    // stage fj: 32 lanes x 4 float4 = 2 KB, coalesced
    const float4* fj4 = (const float4*)(f + (size_t)j * D);
#pragma unroll
    for (int q = 0; q < 4; ++q) {
      int e0 = (hl * 4 + q) * 4;
      *(float4*)&fjs[wave][h][e0 >> 7][e0 & 127] = fj4[hl * 4 + q];
    }

    // chain (lf,m): acc over g=0..15 of fl((a-b)^2), ascending
    const float* ai = fis[lf];
    const float* bi = fjs[wave][h][lf];
    float d0 = ai[m] - bi[m];
    float acc = fbar(d0 * d0);
#pragma unroll
    for (int g = 1; g < 16; ++g) {
      float d = ai[8 * g + m] - bi[8 * g + m];
      acc = acc + fbar(d * d);
    }
    // m-tree: ((r0+r1)+(r2+r3))+((r4+r5)+(r6+r7))  [xor-butterfly, exact]
    float u = acc + __shfl_xor(acc, 1);
    u = u + __shfl_xor(u, 2);
    u = u + __shfl_xor(u, 4);
    // leaf tree: (L0+L1)+(L2+L3)
    float s1 = u + __shfl_xor(u, 8);
    float sq = s1 + __shfl_xor(s1, 16);

    if (hl == 0) {
      float e = sq > 0.0f ? (float)sqrt((double)sq) : 0.0f;
      sval[c] = adj[(size_t)row * N + j] / sa + e / se;
    }
  }
  __syncthreads();

  // wave-parallel top-9: lane c holds (sval[c], ajx[c]); 9 shfl-argmax
  // rounds with the exact comparator; winner removal by unique index.
  if (wave == 0) {
    float v = sval[lane];
    int j = ajx[lane];
    size_t NK = (size_t)N * KP1;
    size_t ob = (size_t)row * KP1;
    for (int r = 0; r < KP1; ++r) {
      float cv = v; int cj = j;
      for (int off = 32; off; off >>= 1) {
        float ov = __shfl_xor(cv, off);
        int oj = __shfl_xor(cj, off);
        if (ov > cv || (ov == cv && oj < cj)) { cv = ov; cj = oj; }
      }
      if (lane == 0) {
        out[ob + r]          = (float)row;  // edge_index row 0 (src)
        out[NK + ob + r]     = (float)cj;   // edge_index row 1 (dst)
        out[2 * NK + ob + r] = cv;          // edge_weights (faithful fp32)
      }
      if (j == cj) v = -2.0f;               // remove winner (j unique)
    }
  }
}

static inline size_t alignup(size_t x, size_t a) { return (x + a - 1) & ~(a - 1); }

extern "C" void kernel_launch(void* const* d_in, const int* in_sizes, int n_in,
                              void* d_out, int out_size, void* d_ws, size_t ws_size,
                              hipStream_t stream) {
  const float* f   = (const float*)d_in[0];
  const float* adj = (const float*)d_in[1];

  long long nn = in_sizes[1];
  int N = (int)llround(sqrt((double)nn));
  int D = in_sizes[0] / N;
  int KP1 = out_size / (3 * N);

  char* w = (char*)d_ws;
  size_t off = 0;
  float* sqn32 = (float*)(w + off); off = alignup(off + (size_t)N * 4, 256);
  float* Sa    = (float*)(w + off); off = alignup(off + (size_t)N * 4, 256);
  float* Se    = (float*)(w + off); off = alignup(off + (size_t)N * 4, 256);
  float* leaf  = (float*)(w + off); off = alignup(off + (size_t)N * 64 * 4, 256);
  int* cand    = (int*)(w + off);   off = alignup(off + (size_t)N * 64 * 4, 256);
  float* cansc = (float*)(w + off); off = alignup(off + (size_t)N * 64 * 4, 256);
  unsigned short* fhi = (unsigned short*)(w + off); off = alignup(off + (size_t)N * D * 2, 256);
  unsigned short* flo = (unsigned short*)(w + off); off = alignup(off + (size_t)N * D * 2, 256);
  unsigned short* eud = (unsigned short*)(w + off); off += (size_t)N * N * 2;
  (void)ws_size;

  int n4 = N * D / 4;
  int NT = N / TBM;
  int nblk = NT * (NT + 1) / 2;
  knn_cvt<<<(n4 + 255) / 256, 256, 0, stream>>>(f, fhi, flo, n4);
  knn_sqn_np<<<N, 128, 0, stream>>>(f, sqn32, N, D);
  knn_gemm_mfma<<<nblk, 256, 0, stream>>>(fhi, flo, sqn32, eud, leaf, N, D);
  knn_rowsel<<<N, 256, 0, stream>>>(adj, eud, leaf, cand, cansc, Sa, Se, N);
  knn_refine<<<N, 256, 0, stream>>>(f, adj, Sa, Se, cand, cansc,
                                    (float*)d_out, N, D, KP1);
}

// Round 19
// 408.180 us; speedup vs baseline: 1.2704x; 1.2704x over previous
//
#include <hip/hip_runtime.h>
#include <hip/hip_bf16.h>
#include <math.h>

// ---------------------------------------------------------------------------
// Hypergraph kNN, fp32-faithful to a numpy float32 reference:
//   eud[i,j] = sqrt( np.sum( (f[i]-f[j])**2 ) )   (DIRECT form, verified r6)
//   distances = adj/np.sum(adj,1) + eud/np.sum(eud,1);  top-9 per row.
// Phase 1: split-bf16 MFMA GEMM (triangular, r14) -> u16 eud + numpy-ordered
//   fp32 leaf sums; rowsel (r19): Sa + Se + tau-compact top-16.
//   r17/r18 aborted: pass-A/pass-B score expressions could contract
//   differently (-ffp-contract=fast) -> C<16 on some row -> uninit gidx ->
//   sentinel index -> OOB fault. r19: (1) fbar-canonicalized score in both
//   passes (bitwise-identical values -> C>=16 proof restored); (2) prefill
//   cand[0..15] with valid indices so refine can NEVER dereference OOB.
// Phase 2: wave-cooperative exact re-score of approx-top-16 (r13/r15),
//   gidx zero-init insurance.
// ---------------------------------------------------------------------------

typedef short bf16x8 __attribute__((ext_vector_type(8)));   // 8 bf16 (4 VGPR)
typedef float f32x4 __attribute__((ext_vector_type(4)));

__device__ __forceinline__ float fbar(float x) {  // pin value; block contract
  asm volatile("" : "+v"(x));
  return x;
}
__device__ __forceinline__ unsigned short f2bf(float x) {  // RNE
  union { float f; unsigned u; } v; v.f = x;
  unsigned r = (v.u + 0x7fffu + ((v.u >> 16) & 1u)) >> 16;
  return (unsigned short)r;
}
__device__ __forceinline__ float bf2f(unsigned short b) {
  union { unsigned u; float f; } v; v.u = ((unsigned)b) << 16; return v.f;
}

// ---- split f32 -> hi/lo bf16 planes ---------------------------------------
__global__ __launch_bounds__(256) void knn_cvt(const float* __restrict__ f,
                                               unsigned short* __restrict__ hi,
                                               unsigned short* __restrict__ lo,
                                               int n4) {
  int i = blockIdx.x * 256 + threadIdx.x;
  if (i >= n4) return;
  float4 v = ((const float4*)f)[i];
  ushort4 h, l;
  h.x = f2bf(v.x); l.x = f2bf(v.x - bf2f(h.x));
  h.y = f2bf(v.y); l.y = f2bf(v.y - bf2f(h.y));
  h.z = f2bf(v.z); l.z = f2bf(v.z - bf2f(h.z));
  h.w = f2bf(v.w); l.w = f2bf(v.w - bf2f(h.w));
  ((ushort4*)hi)[i] = h;
  ((ushort4*)lo)[i] = l;
}

// ---- sq_norms: np.sum(f*f, axis=1) in exact numpy fp32 pairwise order -----
__global__ __launch_bounds__(128) void knn_sqn_np(const float* __restrict__ f,
                                                  float* __restrict__ sqn32,
                                                  int N, int D) {
  int row = blockIdx.x;             // D == 512: 4 leaves of 128
  int t = threadIdx.x;              // 128 threads
  __shared__ float a[512];
  __shared__ float R[4][8];
  const float* fr = f + (size_t)row * D;
  float4 v = ((const float4*)fr)[t];
  a[t * 4 + 0] = v.x * v.x;
  a[t * 4 + 1] = v.y * v.y;
  a[t * 4 + 2] = v.z * v.z;
  a[t * 4 + 3] = v.w * v.w;
  __syncthreads();
  if (t < 32) {
    int lf = t >> 3, m = t & 7;
    float s = a[lf * 128 + m];
    for (int g = 1; g < 16; ++g) s += a[lf * 128 + 8 * g + m];
    R[lf][m] = s;
  }
  __syncthreads();
  if (t == 0) {
    float L[4];
#pragma unroll
    for (int lf = 0; lf < 4; ++lf)
      L[lf] = ((R[lf][0] + R[lf][1]) + (R[lf][2] + R[lf][3])) +
              ((R[lf][4] + R[lf][5]) + (R[lf][6] + R[lf][7]));
    sqn32[row] = (L[0] + L[1]) + (L[2] + L[3]);
  }
}

// ---- split-bf16 MFMA GEMM: 128x128 tile, 4 waves, BK=32, TRIANGULAR -------
#define TBM 128
#define TBN 128
#define TBK 32
__global__ __launch_bounds__(256) void knn_gemm_mfma(
    const unsigned short* __restrict__ fhi, const unsigned short* __restrict__ flo,
    const float* __restrict__ sqn32, unsigned short* __restrict__ eud,
    float* __restrict__ leaf, int N, int D) {
  // aliased LDS: staging (4 x 10240B) in k-loop; epilogue: Et[64][132] (33792)
  // + R2[64][8] (@33792) + R3[128][8] (@35840, persists across passes)
  __shared__ __align__(16) char smem[40960];
  unsigned short (*Ah)[40] = (unsigned short(*)[40])(smem);
  unsigned short (*Al)[40] = (unsigned short(*)[40])(smem + 10240);
  unsigned short (*Bh)[40] = (unsigned short(*)[40])(smem + 20480);
  unsigned short (*Bl)[40] = (unsigned short(*)[40])(smem + 30720);

  int tid = threadIdx.x;

  // triangular decode: block -> (by <= bx)
  int NT = N / TBM;
  int b = blockIdx.x;
  int by = 0, rem = NT;
  while (b >= rem) { b -= rem; ++by; --rem; }
  int bx = by + b;

  int i0 = by * TBM, j0 = bx * TBN;
  int wid = tid >> 6, l = tid & 63;
  int wr = wid >> 1, wc = wid & 1;  // wave -> 64x64 quadrant
  int lr = l & 15, lk = l >> 4;     // frag row, k-chunk

  f32x4 acc[4][4] = {};             // statically indexed only (unrolled)

  int sr = tid >> 1;                // staging row 0..127
  int sh = (tid & 1) << 4;          // k-half 0/16

  for (int k0 = 0; k0 < D; k0 += TBK) {
    size_t aoff = (size_t)(i0 + sr) * D + k0 + sh;
    size_t boff = (size_t)(j0 + sr) * D + k0 + sh;
    *(uint4*)&Ah[sr][sh]     = *(const uint4*)(fhi + aoff);
    *(uint4*)&Ah[sr][sh + 8] = *(const uint4*)(fhi + aoff + 8);
    *(uint4*)&Al[sr][sh]     = *(const uint4*)(flo + aoff);
    *(uint4*)&Al[sr][sh + 8] = *(const uint4*)(flo + aoff + 8);
    *(uint4*)&Bh[sr][sh]     = *(const uint4*)(fhi + boff);
    *(uint4*)&Bh[sr][sh + 8] = *(const uint4*)(fhi + boff + 8);
    *(uint4*)&Bl[sr][sh]     = *(const uint4*)(flo + boff);
    *(uint4*)&Bl[sr][sh + 8] = *(const uint4*)(flo + boff + 8);
    __syncthreads();

    bf16x8 ah[4], al_[4], bh[4], bl_[4];
#pragma unroll
    for (int fr = 0; fr < 4; ++fr) {
      ah[fr]  = *(const bf16x8*)&Ah[wr * 64 + fr * 16 + lr][lk * 8];
      al_[fr] = *(const bf16x8*)&Al[wr * 64 + fr * 16 + lr][lk * 8];
      bh[fr]  = *(const bf16x8*)&Bh[wc * 64 + fr * 16 + lr][lk * 8];
      bl_[fr] = *(const bf16x8*)&Bl[wc * 64 + fr * 16 + lr][lk * 8];
    }
#pragma unroll
    for (int fr = 0; fr < 4; ++fr)
#pragma unroll
      for (int fc = 0; fc < 4; ++fc) {
        acc[fr][fc] = __builtin_amdgcn_mfma_f32_16x16x32_bf16(
            ah[fr], bh[fc], acc[fr][fc], 0, 0, 0);
        acc[fr][fc] = __builtin_amdgcn_mfma_f32_16x16x32_bf16(
            ah[fr], bl_[fc], acc[fr][fc], 0, 0, 0);
        acc[fr][fc] = __builtin_amdgcn_mfma_f32_16x16x32_bf16(
            al_[fr], bh[fc], acc[fr][fc], 0, 0, 0);
      }
    __syncthreads();
  }

  // ---- epilogue ----
  float (*Et)[132] = (float(*)[132])(smem);          // 64 rows x 132 (padded)
  float (*R2)[8]   = (float(*)[8])(smem + 33792);    // standard chains
  float (*R3)[8]   = (float(*)[8])(smem + 35840);    // mirror chains (128x8)

  float sj[4];
#pragma unroll
  for (int fc = 0; fc < 4; ++fc) sj[fc] = sqn32[j0 + wc * 64 + fc * 16 + lr];

  bool mir = (bx != by);

#pragma unroll
  for (int pass = 0; pass < 2; ++pass) {
    if (wr == pass) {
#pragma unroll
      for (int fr = 0; fr < 4; ++fr) {
#pragma unroll
        for (int v = 0; v < 4; ++v) {
          int irow = fr * 16 + lk * 4 + v;          // 0..63 within pass half
          int i = i0 + pass * 64 + irow;
          float si = sqn32[i];
#pragma unroll
          for (int fc = 0; fc < 4; ++fc) {
            int jcol = wc * 64 + fc * 16 + lr;
            int j = j0 + jcol;
            float sq = si + sj[fc] - 2.0f * acc[fr][fc][v];
            float e = (sq > 0.0f && i != j) ? sqrtf(sq) : 0.0f;
            Et[irow][jcol] = e;
            int q = (int)(e * 1024.0f + 0.5f);
            if (q > 65535) q = 65535;
            eud[(size_t)i * N + j] = (unsigned short)q;
          }
        }
      }
    }
    __syncthreads();

    // standard numpy leaf chains: 64 rows x 8 accs, stride-8 ascending
#pragma unroll
    for (int u0 = 0; u0 < 2; ++u0) {
      int u = tid + u0 * 256;                       // 0..511
      int row = u >> 3, m = u & 7;
      float s = Et[row][m];
#pragma unroll
      for (int g = 1; g < 16; ++g) s += Et[row][8 * g + m];
      R2[row][m] = s;
    }

    if (mir) {
      // mirror partial chains: leaf elem idx = 64*pass + 8g + m over Et cols
#pragma unroll
      for (int u0 = 0; u0 < 4; ++u0) {
        int u = tid + u0 * 256;                     // 0..1023
        int jofs = u >> 3, m = u & 7;
        float s = (pass == 0) ? 0.0f : R3[jofs][m];
#pragma unroll
        for (int g = 0; g < 8; ++g) s += Et[8 * g + m][jofs];
        R3[jofs][m] = s;
      }
      // mirror eud write: eud[j][i-range], re-quantized from same floats
      {
        int j = tid >> 1, h = tid & 1;
        size_t base = (size_t)(j0 + j) * N + i0 + pass * 64 + h * 32;
        unsigned short buf[32];
#pragma unroll
        for (int ii = 0; ii < 32; ++ii) {
          float e = Et[h * 32 + ii][j];
          int q = (int)(e * 1024.0f + 0.5f);
          if (q > 65535) q = 65535;
          buf[ii] = (unsigned short)q;
        }
#pragma unroll
        for (int q4 = 0; q4 < 4; ++q4)
          *(uint4*)(eud + base + q4 * 8) = *(uint4*)&buf[q4 * 8];
      }
    }
    __syncthreads();

    if (tid < 64) {
      float v = ((R2[tid][0] + R2[tid][1]) + (R2[tid][2] + R2[tid][3])) +
                ((R2[tid][4] + R2[tid][5]) + (R2[tid][6] + R2[tid][7]));
      leaf[(size_t)(i0 + pass * 64 + tid) * 64 + bx] = v;
    }
    if (mir && pass == 1 && tid < 128) {
      float v = ((R3[tid][0] + R3[tid][1]) + (R3[tid][2] + R3[tid][3])) +
                ((R3[tid][4] + R3[tid][5]) + (R3[tid][6] + R3[tid][7]));
      leaf[(size_t)(j0 + tid) * 64 + by] = v;
    }
    __syncthreads();
  }
}

// ---- rowsel (r19): Sa + Se + tau-compact + rank-based top-16 --------------
// Score canonicalized via fbar in BOTH passes -> bitwise-equal values ->
// tau (16th-largest distinct of 256 thread maxima) guarantees C >= 16.
// Prefill makes every cand slot a valid index regardless (crash insurance).
#define CAP 640
__global__ __launch_bounds__(256) void knn_rowsel(
    const float* __restrict__ adj, const unsigned short* __restrict__ eud,
    const float* __restrict__ leaf, int* __restrict__ cand,
    float* __restrict__ cansc,
    float* __restrict__ SaOut, float* __restrict__ SeOut, int N) {
  __shared__ float arow[8192];
  __shared__ float R[64][8];
  __shared__ float Lf[64];
  __shared__ float bc[2];
  __shared__ int   cnt;
  __shared__ float ls[CAP];
  __shared__ int   lj[CAP];

  int row = blockIdx.x;
  int t = threadIdx.x;
  const float* ar = adj + (size_t)row * N;

  // stage adjacency row (32 KB) once
#pragma unroll
  for (int c = 0; c < 8; ++c)
    ((float4*)arow)[c * 256 + t] = ((const float4*)ar)[c * 256 + t];
  if (t == 0) cnt = 0;
  __syncthreads();

  // Sa: numpy pairwise order — 64 leaves of 128, 8 stride-8 accumulators
  for (int u = t; u < 512; u += 256) {
    int lf = u >> 3, m = u & 7;
    float s = arow[lf * 128 + m];
    for (int g = 1; g < 16; ++g) s += arow[lf * 128 + 8 * g + m];
    R[lf][m] = s;
  }
  __syncthreads();
  if (t < 64)
    Lf[t] = ((R[t][0] + R[t][1]) + (R[t][2] + R[t][3])) +
            ((R[t][4] + R[t][5]) + (R[t][6] + R[t][7]));
  __syncthreads();
  for (int w = 32; w >= 1; w >>= 1) {
    if (t < w) Lf[t] = Lf[2 * t] + Lf[2 * t + 1];
    __syncthreads();
  }
  if (t == 0) { float Sa = Lf[0]; SaOut[row] = Sa; bc[0] = 1.0f / Sa; }
  __syncthreads();

  // Se: balanced tree over the 64 numpy-ordered gemm leaf sums
  if (t < 64) Lf[t] = leaf[(size_t)row * 64 + t];
  __syncthreads();
  for (int w = 32; w >= 1; w >>= 1) {
    if (t < w) Lf[t] = Lf[2 * t] + Lf[2 * t + 1];
    __syncthreads();
  }
  if (t == 0) {
    float Se = Lf[0]; SeOut[row] = Se;
    bc[1] = (float)(1.0 / ((double)Se * 1024.0));
  }
  __syncthreads();
  float ra = bc[0], re = bc[1];

  const unsigned short* er = eud + (size_t)row * N;

  // canonical score: two pinned products + one add (identical both passes)
#define SCORE(avc, evc) (fbar((avc) * ra) + fbar((float)(evc) * re))

  // pass A: per-thread max of its 32 scores. maxv reuses R (float, dead).
  float* maxv = &R[0][0];
  float mx = -3.0e38f;
#pragma unroll
  for (int it = 0; it < 8; ++it) {
    int j = it * 1024 + t * 4;
    float4 av = *(const float4*)(arow + j);
    ushort4 ev = *(const ushort4*)(er + j);
    mx = fmaxf(mx, SCORE(av.x, ev.x));
    mx = fmaxf(mx, SCORE(av.y, ev.y));
    mx = fmaxf(mx, SCORE(av.z, ev.z));
    mx = fmaxf(mx, SCORE(av.w, ev.w));
  }
  maxv[t] = mx;
  __syncthreads();

  // tau: 16th-largest distinct of the 256 maxima — all waves redundantly
  float tau = -3.0e38f;
  {
    int lane = t & 63;
    float a0 = maxv[lane], a1 = maxv[lane + 64];
    float a2 = maxv[lane + 128], a3 = maxv[lane + 192];
#pragma unroll
    for (int r = 0; r < 16; ++r) {
      float cv = fmaxf(fmaxf(a0, a1), fmaxf(a2, a3));
      for (int off = 32; off; off >>= 1) cv = fmaxf(cv, __shfl_xor(cv, off));
      tau = cv;
      if (a0 == cv) a0 = -3.0e38f;
      if (a1 == cv) a1 = -3.0e38f;
      if (a2 == cv) a2 = -3.0e38f;
      if (a3 == cv) a3 = -3.0e38f;
    }
  }
  __syncthreads();

  // pass B: compact all (score, j) with score >= tau (identical SCORE)
#pragma unroll
  for (int it = 0; it < 8; ++it) {
    int j = it * 1024 + t * 4;
    float4 av = *(const float4*)(arow + j);
    ushort4 ev = *(const ushort4*)(er + j);
    float s0 = SCORE(av.x, ev.x);
    float s1 = SCORE(av.y, ev.y);
    float s2 = SCORE(av.z, ev.z);
    float s3 = SCORE(av.w, ev.w);
    if (s0 >= tau) { int p = atomicAdd(&cnt, 1); if (p < CAP) { ls[p] = s0; lj[p] = j + 0; } }
    if (s1 >= tau) { int p = atomicAdd(&cnt, 1); if (p < CAP) { ls[p] = s1; lj[p] = j + 1; } }
    if (s2 >= tau) { int p = atomicAdd(&cnt, 1); if (p < CAP) { ls[p] = s2; lj[p] = j + 2; } }
    if (s3 >= tau) { int p = atomicAdd(&cnt, 1); if (p < CAP) { ls[p] = s3; lj[p] = j + 3; } }
  }
#undef SCORE
  __syncthreads();
  int C = cnt < CAP ? cnt : CAP;

  // prefill ALL 64 slots: 0..15 valid small indices (crash insurance if a
  // rank were ever missed), 16..63 sentinels (rank >= 16 in refine).
  if (t < 64) {
    cand[(size_t)row * 64 + t] = (t < 16) ? t : (0x40000000 + t);
    cansc[(size_t)row * 64 + t] = -3.0e38f;
  }
  __syncthreads();   // prefill ordered before rank-pass overwrites

  // rank pass: element i's rank = #{k: (s_k,j_k) > (s_i,j_i)}; rank<16 wins.
  // Indices unique -> strict total order -> exactly one element per rank.
  for (int i = t; i < C; i += 256) {
    float si = ls[i]; int ji = lj[i];
    int rank = 0;
    for (int k = 0; k < C; ++k) {
      float vk = ls[k]; int jk = lj[k];
      if (vk > si || (vk == si && jk < ji)) ++rank;
    }
    if (rank < 16) {
      cand[(size_t)row * 64 + rank] = ji;
      cansc[(size_t)row * 64 + rank] = si;
    }
  }
}

// ---- phase 2 (r19): wave-cooperative exact re-score of approx-top-16 ------
// [4][136] LDS padding; gidx zero-init insurance; final top-9 via wave-0
// register shfl-argmax (exact same total order).
__global__ __launch_bounds__(256) void knn_refine(
    const float* __restrict__ f, const float* __restrict__ adj,
    const float* __restrict__ Sa, const float* __restrict__ Se,
    const int* __restrict__ cand, const float* __restrict__ cansc,
    float* __restrict__ out, int N, int D, int KP1) {
  int row = blockIdx.x;
  int t = threadIdx.x;
  int wave = t >> 6, lane = t & 63;

  __shared__ float fis[4][136];
  __shared__ float fjs[4][2][4][136];
  __shared__ float sval[64];
  __shared__ float asc[64];
  __shared__ int   ajx[64];
  __shared__ int   gidx[16];

  if (t < 64) {
    ajx[t] = cand[(size_t)row * 64 + t];
    asc[t] = cansc[(size_t)row * 64 + t];
    sval[t] = -3.0e38f;
  }
  if (t >= 64 && t < 80) gidx[t - 64] = 0;   // insurance: valid list pos
  if (t < 128) {
    int e0 = t * 4;
    *(float4*)&fis[e0 >> 7][e0 & 127] =
        ((const float4*)(f + (size_t)row * D))[t];
  }
  __syncthreads();

  // approx rank among the 64 (tie-break: lower index ranks higher)
  if (t < 64) {
    int myj = ajx[t]; float mys = asc[t];
    int rank = 0;
    for (int c = 0; c < 64; ++c) {
      float v = asc[c]; int jc = ajx[c];
      if (v > mys || (v == mys && jc < myj)) ++rank;
    }
    if (rank < 16) gidx[rank] = t;
  }
  __syncthreads();

  float sa = Sa[row], se = Se[row];
  int h = lane >> 5;        // half 0/1 within wave
  int hl = lane & 31;       // lane in half
  int lf = hl >> 3, m = hl & 7;

#pragma unroll
  for (int p = 0; p < 2; ++p) {
    int slot = wave * 4 + p * 2 + h;        // rank slot handled by this half
    int c = gidx[slot];
    int j = ajx[c];

    // stage fj: 32 lanes x 4 float4 = 2 KB, coalesced
    const float4* fj4 = (const float4*)(f + (size_t)j * D);
#pragma unroll
    for (int q = 0; q < 4; ++q) {
      int e0 = (hl * 4 + q) * 4;
      *(float4*)&fjs[wave][h][e0 >> 7][e0 & 127] = fj4[hl * 4 + q];
    }

    // chain (lf,m): acc over g=0..15 of fl((a-b)^2), ascending
    const float* ai = fis[lf];
    const float* bi = fjs[wave][h][lf];
    float d0 = ai[m] - bi[m];
    float acc = fbar(d0 * d0);
#pragma unroll
    for (int g = 1; g < 16; ++g) {
      float d = ai[8 * g + m] - bi[8 * g + m];
      acc = acc + fbar(d * d);
    }
    // m-tree: ((r0+r1)+(r2+r3))+((r4+r5)+(r6+r7))  [xor-butterfly, exact]
    float u = acc + __shfl_xor(acc, 1);
    u = u + __shfl_xor(u, 2);
    u = u + __shfl_xor(u, 4);
    // leaf tree: (L0+L1)+(L2+L3)
    float s1 = u + __shfl_xor(u, 8);
    float sq = s1 + __shfl_xor(s1, 16);

    if (hl == 0) {
      float e = sq > 0.0f ? (float)sqrt((double)sq) : 0.0f;
      sval[c] = adj[(size_t)row * N + j] / sa + e / se;
    }
  }
  __syncthreads();

  // wave-parallel top-9: lane c holds (sval[c], ajx[c]); 9 shfl-argmax
  // rounds with the exact comparator; winner removal by unique index.
  if (wave == 0) {
    float v = sval[lane];
    int j = ajx[lane];
    size_t NK = (size_t)N * KP1;
    size_t ob = (size_t)row * KP1;
    for (int r = 0; r < KP1; ++r) {
      float cv = v; int cj = j;
      for (int off = 32; off; off >>= 1) {
        float ov = __shfl_xor(cv, off);
        int oj = __shfl_xor(cj, off);
        if (ov > cv || (ov == cv && oj < cj)) { cv = ov; cj = oj; }
      }
      if (lane == 0) {
        out[ob + r]          = (float)row;  // edge_index row 0 (src)
        out[NK + ob + r]     = (float)cj;   // edge_index row 1 (dst)
        out[2 * NK + ob + r] = cv;          // edge_weights (faithful fp32)
      }
      if (j == cj) v = -2.0f;               // remove winner (j unique)
    }
  }
}

static inline size_t alignup(size_t x, size_t a) { return (x + a - 1) & ~(a - 1); }

extern "C" void kernel_launch(void* const* d_in, const int* in_sizes, int n_in,
                              void* d_out, int out_size, void* d_ws, size_t ws_size,
                              hipStream_t stream) {
  const float* f   = (const float*)d_in[0];
  const float* adj = (const float*)d_in[1];

  long long nn = in_sizes[1];
  int N = (int)llround(sqrt((double)nn));
  int D = in_sizes[0] / N;
  int KP1 = out_size / (3 * N);

  char* w = (char*)d_ws;
  size_t off = 0;
  float* sqn32 = (float*)(w + off); off = alignup(off + (size_t)N * 4, 256);
  float* Sa    = (float*)(w + off); off = alignup(off + (size_t)N * 4, 256);
  float* Se    = (float*)(w + off); off = alignup(off + (size_t)N * 4, 256);
  float* leaf  = (float*)(w + off); off = alignup(off + (size_t)N * 64 * 4, 256);
  int* cand    = (int*)(w + off);   off = alignup(off + (size_t)N * 64 * 4, 256);
  float* cansc = (float*)(w + off); off = alignup(off + (size_t)N * 64 * 4, 256);
  unsigned short* fhi = (unsigned short*)(w + off); off = alignup(off + (size_t)N * D * 2, 256);
  unsigned short* flo = (unsigned short*)(w + off); off = alignup(off + (size_t)N * D * 2, 256);
  unsigned short* eud = (unsigned short*)(w + off); off += (size_t)N * N * 2;
  (void)ws_size;

  int n4 = N * D / 4;
  int NT = N / TBM;
  int nblk = NT * (NT + 1) / 2;
  knn_cvt<<<(n4 + 255) / 256, 256, 0, stream>>>(f, fhi, flo, n4);
  knn_sqn_np<<<N, 128, 0, stream>>>(f, sqn32, N, D);
  knn_gemm_mfma<<<nblk, 256, 0, stream>>>(fhi, flo, sqn32, eud, leaf, N, D);
  knn_rowsel<<<N, 256, 0, stream>>>(adj, eud, leaf, cand, cansc, Sa, Se, N);
  knn_refine<<<N, 256, 0, stream>>>(f, adj, Sa, Se, cand, cansc,
                                    (float*)d_out, N, D, KP1);
}

// Round 20
// 399.386 us; speedup vs baseline: 1.2984x; 1.0220x over previous
//
#include <hip/hip_runtime.h>
#include <hip/hip_bf16.h>
#include <math.h>

// ---------------------------------------------------------------------------
// Hypergraph kNN, fp32-faithful to a numpy float32 reference:
//   eud[i,j] = sqrt( np.sum( (f[i]-f[j])**2 ) )   (DIRECT form, verified r6)
//   distances = adj/np.sum(adj,1) + eud/np.sum(eud,1);  top-9 per row.
// Phase 1: split-bf16 MFMA GEMM (triangular, r14) -> u16 eud + numpy-ordered
//   fp32 leaf sums. r20: staging via __builtin_amdgcn_global_load_lds
//   (width 16, wave-per-array, XOR k-block swizzle on the global source,
//   matching swizzled ds_read) — removes the VGPR round-trip and cuts the
//   8-way frag-read bank aliasing to 4-way. MFMA inputs bitwise unchanged.
// rowsel (r19): Sa + Se + fbar-canonical tau-compact top-16 (C>=16 proof).
// Phase 2: wave-cooperative exact re-score of approx-top-16 (r13/r15/r19).
// ---------------------------------------------------------------------------

typedef short bf16x8 __attribute__((ext_vector_type(8)));   // 8 bf16 (4 VGPR)
typedef float f32x4 __attribute__((ext_vector_type(4)));

__device__ __forceinline__ float fbar(float x) {  // pin value; block contract
  asm volatile("" : "+v"(x));
  return x;
}
__device__ __forceinline__ unsigned short f2bf(float x) {  // RNE
  union { float f; unsigned u; } v; v.f = x;
  unsigned r = (v.u + 0x7fffu + ((v.u >> 16) & 1u)) >> 16;
  return (unsigned short)r;
}
__device__ __forceinline__ float bf2f(unsigned short b) {
  union { unsigned u; float f; } v; v.u = ((unsigned)b) << 16; return v.f;
}
__device__ __forceinline__ void gload_lds16(const void* g, void* l) {
  __builtin_amdgcn_global_load_lds(
      (const __attribute__((address_space(1))) unsigned int*)g,
      (__attribute__((address_space(3))) unsigned int*)l, 16, 0, 0);
}

// ---- split f32 -> hi/lo bf16 planes ---------------------------------------
__global__ __launch_bounds__(256) void knn_cvt(const float* __restrict__ f,
                                               unsigned short* __restrict__ hi,
                                               unsigned short* __restrict__ lo,
                                               int n4) {
  int i = blockIdx.x * 256 + threadIdx.x;
  if (i >= n4) return;
  float4 v = ((const float4*)f)[i];
  ushort4 h, l;
  h.x = f2bf(v.x); l.x = f2bf(v.x - bf2f(h.x));
  h.y = f2bf(v.y); l.y = f2bf(v.y - bf2f(h.y));
  h.z = f2bf(v.z); l.z = f2bf(v.z - bf2f(h.z));
  h.w = f2bf(v.w); l.w = f2bf(v.w - bf2f(h.w));
  ((ushort4*)hi)[i] = h;
  ((ushort4*)lo)[i] = l;
}

// ---- sq_norms: np.sum(f*f, axis=1) in exact numpy fp32 pairwise order -----
__global__ __launch_bounds__(128) void knn_sqn_np(const float* __restrict__ f,
                                                  float* __restrict__ sqn32,
                                                  int N, int D) {
  int row = blockIdx.x;             // D == 512: 4 leaves of 128
  int t = threadIdx.x;              // 128 threads
  __shared__ float a[512];
  __shared__ float R[4][8];
  const float* fr = f + (size_t)row * D;
  float4 v = ((const float4*)fr)[t];
  a[t * 4 + 0] = v.x * v.x;
  a[t * 4 + 1] = v.y * v.y;
  a[t * 4 + 2] = v.z * v.z;
  a[t * 4 + 3] = v.w * v.w;
  __syncthreads();
  if (t < 32) {
    int lf = t >> 3, m = t & 7;
    float s = a[lf * 128 + m];
    for (int g = 1; g < 16; ++g) s += a[lf * 128 + 8 * g + m];
    R[lf][m] = s;
  }
  __syncthreads();
  if (t == 0) {
    float L[4];
#pragma unroll
    for (int lf = 0; lf < 4; ++lf)
      L[lf] = ((R[lf][0] + R[lf][1]) + (R[lf][2] + R[lf][3])) +
              ((R[lf][4] + R[lf][5]) + (R[lf][6] + R[lf][7]));
    sqn32[row] = (L[0] + L[1]) + (L[2] + L[3]);
  }
}

// ---- split-bf16 MFMA GEMM: 128x128 tile, 4 waves, BK=32, TRIANGULAR -------
// r20 staging: 4 arrays [128][32] u16 (unpadded, 8 KB each) at smem+wid*8192;
// wave wid stages its array via global_load_lds width 16. Physical 16B block
// p of row r holds logical k-block (p ^ (r&3)); frag reads use lk^(row&3).
#define TBM 128
#define TBN 128
#define TBK 32
__global__ __launch_bounds__(256) void knn_gemm_mfma(
    const unsigned short* __restrict__ fhi, const unsigned short* __restrict__ flo,
    const float* __restrict__ sqn32, unsigned short* __restrict__ eud,
    float* __restrict__ leaf, int N, int D) {
  // aliased LDS: staging (4 x 8192B) in k-loop; epilogue: Et[64][132] (33792)
  // + R2[64][8] (@33792) + R3[128][8] (@35840, persists across passes)
  __shared__ __align__(16) char smem[40960];

  int tid = threadIdx.x;

  // triangular decode: block -> (by <= bx)
  int NT = N / TBM;
  int b = blockIdx.x;
  int by = 0, rem = NT;
  while (b >= rem) { b -= rem; ++by; --rem; }
  int bx = by + b;

  int i0 = by * TBM, j0 = bx * TBN;
  int wid = tid >> 6, l = tid & 63;
  int wr = wid >> 1, wc = wid & 1;  // wave -> 64x64 quadrant
  int lr = l & 15, lk = l >> 4;     // frag row, k-chunk

  f32x4 acc[4][4] = {};             // statically indexed only (unrolled)

  // staging geometry (wave wid stages array wid: Ah, Al, Bh, Bl)
  const unsigned short* gp = (wid & 1) ? flo : fhi;
  int rbase = (wid < 2) ? i0 : j0;
  unsigned short* Lp = (unsigned short*)(smem + wid * 8192);
  int lrow = l >> 2;                // 0..15
  int lblk = l & 3;                 // physical 16B block within row
  int kblk = lblk ^ (lrow & 3);     // logical k-block this lane fetches

  const unsigned short* A_h = (const unsigned short*)(smem);
  const unsigned short* A_l = (const unsigned short*)(smem + 8192);
  const unsigned short* B_h = (const unsigned short*)(smem + 16384);
  const unsigned short* B_l = (const unsigned short*)(smem + 24576);

  for (int k0 = 0; k0 < D; k0 += TBK) {
#pragma unroll
    for (int i = 0; i < 8; ++i) {
      int r = i * 16 + lrow;
      const unsigned short* g = gp + (size_t)(rbase + r) * D + k0 + kblk * 8;
      gload_lds16(g, Lp + (size_t)r * 32 + lblk * 8);
    }
    __syncthreads();

    bf16x8 ah[4], al_[4], bh[4], bl_[4];
#pragma unroll
    for (int fr = 0; fr < 4; ++fr) {
      int ra = wr * 64 + fr * 16 + lr;
      int rb = wc * 64 + fr * 16 + lr;
      int ka = (lk ^ (ra & 3)) * 8;
      int kb = (lk ^ (rb & 3)) * 8;
      ah[fr]  = *(const bf16x8*)(A_h + (size_t)ra * 32 + ka);
      al_[fr] = *(const bf16x8*)(A_l + (size_t)ra * 32 + ka);
      bh[fr]  = *(const bf16x8*)(B_h + (size_t)rb * 32 + kb);
      bl_[fr] = *(const bf16x8*)(B_l + (size_t)rb * 32 + kb);
    }
#pragma unroll
    for (int fr = 0; fr < 4; ++fr)
#pragma unroll
      for (int fc = 0; fc < 4; ++fc) {
        acc[fr][fc] = __builtin_amdgcn_mfma_f32_16x16x32_bf16(
            ah[fr], bh[fc], acc[fr][fc], 0, 0, 0);
        acc[fr][fc] = __builtin_amdgcn_mfma_f32_16x16x32_bf16(
            ah[fr], bl_[fc], acc[fr][fc], 0, 0, 0);
        acc[fr][fc] = __builtin_amdgcn_mfma_f32_16x16x32_bf16(
            al_[fr], bh[fc], acc[fr][fc], 0, 0, 0);
      }
    __syncthreads();
  }

  // ---- epilogue ----
  float (*Et)[132] = (float(*)[132])(smem);          // 64 rows x 132 (padded)
  float (*R2)[8]   = (float(*)[8])(smem + 33792);    // standard chains
  float (*R3)[8]   = (float(*)[8])(smem + 35840);    // mirror chains (128x8)

  float sj[4];
#pragma unroll
  for (int fc = 0; fc < 4; ++fc) sj[fc] = sqn32[j0 + wc * 64 + fc * 16 + lr];

  bool mir = (bx != by);

#pragma unroll
  for (int pass = 0; pass < 2; ++pass) {
    if (wr == pass) {
#pragma unroll
      for (int fr = 0; fr < 4; ++fr) {
#pragma unroll
        for (int v = 0; v < 4; ++v) {
          int irow = fr * 16 + lk * 4 + v;          // 0..63 within pass half
          int i = i0 + pass * 64 + irow;
          float si = sqn32[i];
#pragma unroll
          for (int fc = 0; fc < 4; ++fc) {
            int jcol = wc * 64 + fc * 16 + lr;
            int j = j0 + jcol;
            float sq = si + sj[fc] - 2.0f * acc[fr][fc][v];
            float e = (sq > 0.0f && i != j) ? sqrtf(sq) : 0.0f;
            Et[irow][jcol] = e;
            int q = (int)(e * 1024.0f + 0.5f);
            if (q > 65535) q = 65535;
            eud[(size_t)i * N + j] = (unsigned short)q;
          }
        }
      }
    }
    __syncthreads();

    // standard numpy leaf chains: 64 rows x 8 accs, stride-8 ascending
#pragma unroll
    for (int u0 = 0; u0 < 2; ++u0) {
      int u = tid + u0 * 256;                       // 0..511
      int row = u >> 3, m = u & 7;
      float s = Et[row][m];
#pragma unroll
      for (int g = 1; g < 16; ++g) s += Et[row][8 * g + m];
      R2[row][m] = s;
    }

    if (mir) {
      // mirror partial chains: leaf elem idx = 64*pass + 8g + m over Et cols
#pragma unroll
      for (int u0 = 0; u0 < 4; ++u0) {
        int u = tid + u0 * 256;                     // 0..1023
        int jofs = u >> 3, m = u & 7;
        float s = (pass == 0) ? 0.0f : R3[jofs][m];
#pragma unroll
        for (int g = 0; g < 8; ++g) s += Et[8 * g + m][jofs];
        R3[jofs][m] = s;
      }
      // mirror eud write: eud[j][i-range], re-quantized from same floats
      {
        int j = tid >> 1, h = tid & 1;
        size_t base = (size_t)(j0 + j) * N + i0 + pass * 64 + h * 32;
        unsigned short buf[32];
#pragma unroll
        for (int ii = 0; ii < 32; ++ii) {
          float e = Et[h * 32 + ii][j];
          int q = (int)(e * 1024.0f + 0.5f);
          if (q > 65535) q = 65535;
          buf[ii] = (unsigned short)q;
        }
#pragma unroll
        for (int q4 = 0; q4 < 4; ++q4)
          *(uint4*)(eud + base + q4 * 8) = *(uint4*)&buf[q4 * 8];
      }
    }
    __syncthreads();

    if (tid < 64) {
      float v = ((R2[tid][0] + R2[tid][1]) + (R2[tid][2] + R2[tid][3])) +
                ((R2[tid][4] + R2[tid][5]) + (R2[tid][6] + R2[tid][7]));
      leaf[(size_t)(i0 + pass * 64 + tid) * 64 + bx] = v;
    }
    if (mir && pass == 1 && tid < 128) {
      float v = ((R3[tid][0] + R3[tid][1]) + (R3[tid][2] + R3[tid][3])) +
                ((R3[tid][4] + R3[tid][5]) + (R3[tid][6] + R3[tid][7]));
      leaf[(size_t)(j0 + tid) * 64 + by] = v;
    }
    __syncthreads();
  }
}

// ---- rowsel (r19): Sa + Se + tau-compact + rank-based top-16 --------------
// Score canonicalized via fbar in BOTH passes -> bitwise-equal values ->
// tau (16th-largest distinct of 256 thread maxima) guarantees C >= 16.
// Prefill makes every cand slot a valid index regardless (crash insurance).
#define CAP 640
__global__ __launch_bounds__(256) void knn_rowsel(
    const float* __restrict__ adj, const unsigned short* __restrict__ eud,
    const float* __restrict__ leaf, int* __restrict__ cand,
    float* __restrict__ cansc,
    float* __restrict__ SaOut, float* __restrict__ SeOut, int N) {
  __shared__ float arow[8192];
  __shared__ float R[64][8];
  __shared__ float Lf[64];
  __shared__ float bc[2];
  __shared__ int   cnt;
  __shared__ float ls[CAP];
  __shared__ int   lj[CAP];

  int row = blockIdx.x;
  int t = threadIdx.x;
  const float* ar = adj + (size_t)row * N;

  // stage adjacency row (32 KB) once
#pragma unroll
  for (int c = 0; c < 8; ++c)
    ((float4*)arow)[c * 256 + t] = ((const float4*)ar)[c * 256 + t];
  if (t == 0) cnt = 0;
  __syncthreads();

  // Sa: numpy pairwise order — 64 leaves of 128, 8 stride-8 accumulators
  for (int u = t; u < 512; u += 256) {
    int lf = u >> 3, m = u & 7;
    float s = arow[lf * 128 + m];
    for (int g = 1; g < 16; ++g) s += arow[lf * 128 + 8 * g + m];
    R[lf][m] = s;
  }
  __syncthreads();
  if (t < 64)
    Lf[t] = ((R[t][0] + R[t][1]) + (R[t][2] + R[t][3])) +
            ((R[t][4] + R[t][5]) + (R[t][6] + R[t][7]));
  __syncthreads();
  for (int w = 32; w >= 1; w >>= 1) {
    if (t < w) Lf[t] = Lf[2 * t] + Lf[2 * t + 1];
    __syncthreads();
  }
  if (t == 0) { float Sa = Lf[0]; SaOut[row] = Sa; bc[0] = 1.0f / Sa; }
  __syncthreads();

  // Se: balanced tree over the 64 numpy-ordered gemm leaf sums
  if (t < 64) Lf[t] = leaf[(size_t)row * 64 + t];
  __syncthreads();
  for (int w = 32; w >= 1; w >>= 1) {
    if (t < w) Lf[t] = Lf[2 * t] + Lf[2 * t + 1];
    __syncthreads();
  }
  if (t == 0) {
    float Se = Lf[0]; SeOut[row] = Se;
    bc[1] = (float)(1.0 / ((double)Se * 1024.0));
  }
  __syncthreads();
  float ra = bc[0], re = bc[1];

  const unsigned short* er = eud + (size_t)row * N;

  // canonical score: two pinned products + one add (identical both passes)
#define SCORE(avc, evc) (fbar((avc) * ra) + fbar((float)(evc) * re))

  // pass A: per-thread max of its 32 scores. maxv reuses R (float, dead).
  float* maxv = &R[0][0];
  float mx = -3.0e38f;
#pragma unroll
  for (int it = 0; it < 8; ++it) {
    int j = it * 1024 + t * 4;
    float4 av = *(const float4*)(arow + j);
    ushort4 ev = *(const ushort4*)(er + j);
    mx = fmaxf(mx, SCORE(av.x, ev.x));
    mx = fmaxf(mx, SCORE(av.y, ev.y));
    mx = fmaxf(mx, SCORE(av.z, ev.z));
    mx = fmaxf(mx, SCORE(av.w, ev.w));
  }
  maxv[t] = mx;
  __syncthreads();

  // tau: 16th-largest distinct of the 256 maxima — all waves redundantly
  float tau = -3.0e38f;
  {
    int lane = t & 63;
    float a0 = maxv[lane], a1 = maxv[lane + 64];
    float a2 = maxv[lane + 128], a3 = maxv[lane + 192];
#pragma unroll
    for (int r = 0; r < 16; ++r) {
      float cv = fmaxf(fmaxf(a0, a1), fmaxf(a2, a3));
      for (int off = 32; off; off >>= 1) cv = fmaxf(cv, __shfl_xor(cv, off));
      tau = cv;
      if (a0 == cv) a0 = -3.0e38f;
      if (a1 == cv) a1 = -3.0e38f;
      if (a2 == cv) a2 = -3.0e38f;
      if (a3 == cv) a3 = -3.0e38f;
    }
  }
  __syncthreads();

  // pass B: compact all (score, j) with score >= tau (identical SCORE)
#pragma unroll
  for (int it = 0; it < 8; ++it) {
    int j = it * 1024 + t * 4;
    float4 av = *(const float4*)(arow + j);
    ushort4 ev = *(const ushort4*)(er + j);
    float s0 = SCORE(av.x, ev.x);
    float s1 = SCORE(av.y, ev.y);
    float s2 = SCORE(av.z, ev.z);
    float s3 = SCORE(av.w, ev.w);
    if (s0 >= tau) { int p = atomicAdd(&cnt, 1); if (p < CAP) { ls[p] = s0; lj[p] = j + 0; } }
    if (s1 >= tau) { int p = atomicAdd(&cnt, 1); if (p < CAP) { ls[p] = s1; lj[p] = j + 1; } }
    if (s2 >= tau) { int p = atomicAdd(&cnt, 1); if (p < CAP) { ls[p] = s2; lj[p] = j + 2; } }
    if (s3 >= tau) { int p = atomicAdd(&cnt, 1); if (p < CAP) { ls[p] = s3; lj[p] = j + 3; } }
  }
#undef SCORE
  __syncthreads();
  int C = cnt < CAP ? cnt : CAP;

  // prefill ALL 64 slots: 0..15 valid small indices (crash insurance if a
  // rank were ever missed), 16..63 sentinels (rank >= 16 in refine).
  if (t < 64) {
    cand[(size_t)row * 64 + t] = (t < 16) ? t : (0x40000000 + t);
    cansc[(size_t)row * 64 + t] = -3.0e38f;
  }
  __syncthreads();   // prefill ordered before rank-pass overwrites

  // rank pass: element i's rank = #{k: (s_k,j_k) > (s_i,j_i)}; rank<16 wins.
  // Indices unique -> strict total order -> exactly one element per rank.
  for (int i = t; i < C; i += 256) {
    float si = ls[i]; int ji = lj[i];
    int rank = 0;
    for (int k = 0; k < C; ++k) {
      float vk = ls[k]; int jk = lj[k];
      if (vk > si || (vk == si && jk < ji)) ++rank;
    }
    if (rank < 16) {
      cand[(size_t)row * 64 + rank] = ji;
      cansc[(size_t)row * 64 + rank] = si;
    }
  }
}

// ---- phase 2 (r19): wave-cooperative exact re-score of approx-top-16 ------
// [4][136] LDS padding; gidx zero-init insurance; final top-9 via wave-0
// register shfl-argmax (exact same total order).
__global__ __launch_bounds__(256) void knn_refine(
    const float* __restrict__ f, const float* __restrict__ adj,
    const float* __restrict__ Sa, const float* __restrict__ Se,
    const int* __restrict__ cand, const float* __restrict__ cansc,
    float* __restrict__ out, int N, int D, int KP1) {
  int row = blockIdx.x;
  int t = threadIdx.x;
  int wave = t >> 6, lane = t & 63;

  __shared__ float fis[4][136];
  __shared__ float fjs[4][2][4][136];
  __shared__ float sval[64];
  __shared__ float asc[64];
  __shared__ int   ajx[64];
  __shared__ int   gidx[16];

  if (t < 64) {
    ajx[t] = cand[(size_t)row * 64 + t];
    asc[t] = cansc[(size_t)row * 64 + t];
    sval[t] = -3.0e38f;
  }
  if (t >= 64 && t < 80) gidx[t - 64] = 0;   // insurance: valid list pos
  if (t < 128) {
    int e0 = t * 4;
    *(float4*)&fis[e0 >> 7][e0 & 127] =
        ((const float4*)(f + (size_t)row * D))[t];
  }
  __syncthreads();

  // approx rank among the 64 (tie-break: lower index ranks higher)
  if (t < 64) {
    int myj = ajx[t]; float mys = asc[t];
    int rank = 0;
    for (int c = 0; c < 64; ++c) {
      float v = asc[c]; int jc = ajx[c];
      if (v > mys || (v == mys && jc < myj)) ++rank;
    }
    if (rank < 16) gidx[rank] = t;
  }
  __syncthreads();

  float sa = Sa[row], se = Se[row];
  int h = lane >> 5;        // half 0/1 within wave
  int hl = lane & 31;       // lane in half
  int lf = hl >> 3, m = hl & 7;

#pragma unroll
  for (int p = 0; p < 2; ++p) {
    int slot = wave * 4 + p * 2 + h;        // rank slot handled by this half
    int c = gidx[slot];
    int j = ajx[c];

    // stage fj: 32 lanes x 4 float4 = 2 KB, coalesced
    const float4* fj4 = (const float4*)(f + (size_t)j * D);
#pragma unroll
    for (int q = 0; q < 4; ++q) {
      int e0 = (hl * 4 + q) * 4;
      *(float4*)&fjs[wave][h][e0 >> 7][e0 & 127] = fj4[hl * 4 + q];
    }

    // chain (lf,m): acc over g=0..15 of fl((a-b)^2), ascending
    const float* ai = fis[lf];
    const float* bi = fjs[wave][h][lf];
    float d0 = ai[m] - bi[m];
    float acc = fbar(d0 * d0);
#pragma unroll
    for (int g = 1; g < 16; ++g) {
      float d = ai[8 * g + m] - bi[8 * g + m];
      acc = acc + fbar(d * d);
    }
    // m-tree: ((r0+r1)+(r2+r3))+((r4+r5)+(r6+r7))  [xor-butterfly, exact]
    float u = acc + __shfl_xor(acc, 1);
    u = u + __shfl_xor(u, 2);
    u = u + __shfl_xor(u, 4);
    // leaf tree: (L0+L1)+(L2+L3)
    float s1 = u + __shfl_xor(u, 8);
    float sq = s1 + __shfl_xor(s1, 16);

    if (hl == 0) {
      float e = sq > 0.0f ? (float)sqrt((double)sq) : 0.0f;
      sval[c] = adj[(size_t)row * N + j] / sa + e / se;
    }
  }
  __syncthreads();

  // wave-parallel top-9: lane c holds (sval[c], ajx[c]); 9 shfl-argmax
  // rounds with the exact comparator; winner removal by unique index.
  if (wave == 0) {
    float v = sval[lane];
    int j = ajx[lane];
    size_t NK = (size_t)N * KP1;
    size_t ob = (size_t)row * KP1;
    for (int r = 0; r < KP1; ++r) {
      float cv = v; int cj = j;
      for (int off = 32; off; off >>= 1) {
        float ov = __shfl_xor(cv, off);
        int oj = __shfl_xor(cj, off);
        if (ov > cv || (ov == cv && oj < cj)) { cv = ov; cj = oj; }
      }
      if (lane == 0) {
        out[ob + r]          = (float)row;  // edge_index row 0 (src)
        out[NK + ob + r]     = (float)cj;   // edge_index row 1 (dst)
        out[2 * NK + ob + r] = cv;          // edge_weights (faithful fp32)
      }
      if (j == cj) v = -2.0f;               // remove winner (j unique)
    }
  }
}

static inline size_t alignup(size_t x, size_t a) { return (x + a - 1) & ~(a - 1); }

extern "C" void kernel_launch(void* const* d_in, const int* in_sizes, int n_in,
                              void* d_out, int out_size, void* d_ws, size_t ws_size,
                              hipStream_t stream) {
  const float* f   = (const float*)d_in[0];
  const float* adj = (const float*)d_in[1];

  long long nn = in_sizes[1];
  int N = (int)llround(sqrt((double)nn));
  int D = in_sizes[0] / N;
  int KP1 = out_size / (3 * N);

  char* w = (char*)d_ws;
  size_t off = 0;
  float* sqn32 = (float*)(w + off); off = alignup(off + (size_t)N * 4, 256);
  float* Sa    = (float*)(w + off); off = alignup(off + (size_t)N * 4, 256);
  float* Se    = (float*)(w + off); off = alignup(off + (size_t)N * 4, 256);
  float* leaf  = (float*)(w + off); off = alignup(off + (size_t)N * 64 * 4, 256);
  int* cand    = (int*)(w + off);   off = alignup(off + (size_t)N * 64 * 4, 256);
  float* cansc = (float*)(w + off); off = alignup(off + (size_t)N * 64 * 4, 256);
  unsigned short* fhi = (unsigned short*)(w + off); off = alignup(off + (size_t)N * D * 2, 256);
  unsigned short* flo = (unsigned short*)(w + off); off = alignup(off + (size_t)N * D * 2, 256);
  unsigned short* eud = (unsigned short*)(w + off); off += (size_t)N * N * 2;
  (void)ws_size;

  int n4 = N * D / 4;
  int NT = N / TBM;
  int nblk = NT * (NT + 1) / 2;
  knn_cvt<<<(n4 + 255) / 256, 256, 0, stream>>>(f, fhi, flo, n4);
  knn_sqn_np<<<N, 128, 0, stream>>>(f, sqn32, N, D);
  knn_gemm_mfma<<<nblk, 256, 0, stream>>>(fhi, flo, sqn32, eud, leaf, N, D);
  knn_rowsel<<<N, 256, 0, stream>>>(adj, eud, leaf, cand, cansc, Sa, Se, N);
  knn_refine<<<N, 256, 0, stream>>>(f, adj, Sa, Se, cand, cansc,
                                    (float*)d_out, N, D, KP1);
}

// Round 21
// 395.115 us; speedup vs baseline: 1.3125x; 1.0108x over previous
//
#include <hip/hip_runtime.h>
#include <hip/hip_bf16.h>
#include <math.h>

// ---------------------------------------------------------------------------
// Hypergraph kNN, fp32-faithful to a numpy float32 reference:
//   eud[i,j] = sqrt( np.sum( (f[i]-f[j])**2 ) )   (DIRECT form, verified r6)
//   distances = adj/np.sum(adj,1) + eud/np.sum(eud,1);  top-9 per row.
// Phase 1: split-bf16 MFMA GEMM (triangular) -> u16 eud + numpy-ordered fp32
//   leaf sums. r21: 2-phase double-buffered staging — issue next tile's
//   global_load_lds (width 16, XOR k-block swizzle) BEFORE the current
//   tile's ds_read+MFMA; one barrier/iter whose implicit vmcnt(0) drains.
//   Loads hide under 48 MFMA. MFMA inputs bitwise unchanged.
// rowsel (r19): Sa + Se + fbar-canonical tau-compact top-16 (C>=16 proof).
// Phase 2: wave-cooperative exact re-score of approx-top-16 (r13/r15/r19).
// ---------------------------------------------------------------------------

typedef short bf16x8 __attribute__((ext_vector_type(8)));   // 8 bf16 (4 VGPR)
typedef float f32x4 __attribute__((ext_vector_type(4)));

__device__ __forceinline__ float fbar(float x) {  // pin value; block contract
  asm volatile("" : "+v"(x));
  return x;
}
__device__ __forceinline__ unsigned short f2bf(float x) {  // RNE
  union { float f; unsigned u; } v; v.f = x;
  unsigned r = (v.u + 0x7fffu + ((v.u >> 16) & 1u)) >> 16;
  return (unsigned short)r;
}
__device__ __forceinline__ float bf2f(unsigned short b) {
  union { unsigned u; float f; } v; v.u = ((unsigned)b) << 16; return v.f;
}
__device__ __forceinline__ void gload_lds16(const void* g, void* l) {
  __builtin_amdgcn_global_load_lds(
      (const __attribute__((address_space(1))) unsigned int*)g,
      (__attribute__((address_space(3))) unsigned int*)l, 16, 0, 0);
}

// ---- split f32 -> hi/lo bf16 planes ---------------------------------------
__global__ __launch_bounds__(256) void knn_cvt(const float* __restrict__ f,
                                               unsigned short* __restrict__ hi,
                                               unsigned short* __restrict__ lo,
                                               int n4) {
  int i = blockIdx.x * 256 + threadIdx.x;
  if (i >= n4) return;
  float4 v = ((const float4*)f)[i];
  ushort4 h, l;
  h.x = f2bf(v.x); l.x = f2bf(v.x - bf2f(h.x));
  h.y = f2bf(v.y); l.y = f2bf(v.y - bf2f(h.y));
  h.z = f2bf(v.z); l.z = f2bf(v.z - bf2f(h.z));
  h.w = f2bf(v.w); l.w = f2bf(v.w - bf2f(h.w));
  ((ushort4*)hi)[i] = h;
  ((ushort4*)lo)[i] = l;
}

// ---- sq_norms: np.sum(f*f, axis=1) in exact numpy fp32 pairwise order -----
__global__ __launch_bounds__(128) void knn_sqn_np(const float* __restrict__ f,
                                                  float* __restrict__ sqn32,
                                                  int N, int D) {
  int row = blockIdx.x;             // D == 512: 4 leaves of 128
  int t = threadIdx.x;              // 128 threads
  __shared__ float a[512];
  __shared__ float R[4][8];
  const float* fr = f + (size_t)row * D;
  float4 v = ((const float4*)fr)[t];
  a[t * 4 + 0] = v.x * v.x;
  a[t * 4 + 1] = v.y * v.y;
  a[t * 4 + 2] = v.z * v.z;
  a[t * 4 + 3] = v.w * v.w;
  __syncthreads();
  if (t < 32) {
    int lf = t >> 3, m = t & 7;
    float s = a[lf * 128 + m];
    for (int g = 1; g < 16; ++g) s += a[lf * 128 + 8 * g + m];
    R[lf][m] = s;
  }
  __syncthreads();
  if (t == 0) {
    float L[4];
#pragma unroll
    for (int lf = 0; lf < 4; ++lf)
      L[lf] = ((R[lf][0] + R[lf][1]) + (R[lf][2] + R[lf][3])) +
              ((R[lf][4] + R[lf][5]) + (R[lf][6] + R[lf][7]));
    sqn32[row] = (L[0] + L[1]) + (L[2] + L[3]);
  }
}

// ---- split-bf16 MFMA GEMM: 128x128 tile, 4 waves, BK=32, TRIANGULAR -------
// r21: double-buffered staging (2 x 32 KB), one barrier/iter; wave wid
// stages array wid of the NEXT tile while MFMA consumes the current one.
// Physical 16B block p of row r holds logical k-block (p ^ (r&3)).
#define TBM 128
#define TBN 128
#define TBK 32
__global__ __launch_bounds__(256) void knn_gemm_mfma(
    const unsigned short* __restrict__ fhi, const unsigned short* __restrict__ flo,
    const float* __restrict__ sqn32, unsigned short* __restrict__ eud,
    float* __restrict__ leaf, int N, int D) {
  // LDS: 2 staging buffers (32768 B each); epilogue aliases the first 40 KB:
  // Et[64][132] (33792) + R2[64][8] (@33792) + R3[128][8] (@35840)
  __shared__ __align__(16) char smem[65536];

  int tid = threadIdx.x;

  // triangular decode: block -> (by <= bx)
  int NT = N / TBM;
  int b = blockIdx.x;
  int by = 0, rem = NT;
  while (b >= rem) { b -= rem; ++by; --rem; }
  int bx = by + b;

  int i0 = by * TBM, j0 = bx * TBN;
  int wid = tid >> 6, l = tid & 63;
  int wr = wid >> 1, wc = wid & 1;  // wave -> 64x64 quadrant
  int lr = l & 15, lk = l >> 4;     // frag row, k-chunk

  f32x4 acc[4][4] = {};             // statically indexed only (unrolled)

  // staging geometry (wave wid stages array wid: Ah, Al, Bh, Bl)
  const unsigned short* gp = (wid & 1) ? flo : fhi;
  int rbase = (wid < 2) ? i0 : j0;
  int lrow = l >> 2;                // 0..15
  int lblk = l & 3;                 // physical 16B block within row
  int kblk = lblk ^ (lrow & 3);     // logical k-block this lane fetches

  // prologue: stage tile k0=0 into buffer 0
  {
    unsigned short* Lp = (unsigned short*)(smem + wid * 8192);
#pragma unroll
    for (int i = 0; i < 8; ++i) {
      int r = i * 16 + lrow;
      const unsigned short* g = gp + (size_t)(rbase + r) * D + kblk * 8;
      gload_lds16(g, Lp + (size_t)r * 32 + lblk * 8);
    }
  }

  int buf = 0;
  for (int k0 = 0; k0 < D; k0 += TBK) {
    __syncthreads();   // implicit vmcnt(0): stage for current buffer drained

    // issue next tile's stage into the other buffer (flies under MFMA)
    if (k0 + TBK < D) {
      unsigned short* Lp = (unsigned short*)(smem + (buf ^ 1) * 32768 + wid * 8192);
#pragma unroll
      for (int i = 0; i < 8; ++i) {
        int r = i * 16 + lrow;
        const unsigned short* g =
            gp + (size_t)(rbase + r) * D + (k0 + TBK) + kblk * 8;
        gload_lds16(g, Lp + (size_t)r * 32 + lblk * 8);
      }
    }

    const char* base = smem + buf * 32768;
    const unsigned short* A_h = (const unsigned short*)(base);
    const unsigned short* A_l = (const unsigned short*)(base + 8192);
    const unsigned short* B_h = (const unsigned short*)(base + 16384);
    const unsigned short* B_l = (const unsigned short*)(base + 24576);

    bf16x8 ah[4], al_[4], bh[4], bl_[4];
#pragma unroll
    for (int fr = 0; fr < 4; ++fr) {
      int ra = wr * 64 + fr * 16 + lr;
      int rb = wc * 64 + fr * 16 + lr;
      int ka = (lk ^ (ra & 3)) * 8;
      int kb = (lk ^ (rb & 3)) * 8;
      ah[fr]  = *(const bf16x8*)(A_h + (size_t)ra * 32 + ka);
      al_[fr] = *(const bf16x8*)(A_l + (size_t)ra * 32 + ka);
      bh[fr]  = *(const bf16x8*)(B_h + (size_t)rb * 32 + kb);
      bl_[fr] = *(const bf16x8*)(B_l + (size_t)rb * 32 + kb);
    }
#pragma unroll
    for (int fr = 0; fr < 4; ++fr)
#pragma unroll
      for (int fc = 0; fc < 4; ++fc) {
        acc[fr][fc] = __builtin_amdgcn_mfma_f32_16x16x32_bf16(
            ah[fr], bh[fc], acc[fr][fc], 0, 0, 0);
        acc[fr][fc] = __builtin_amdgcn_mfma_f32_16x16x32_bf16(
            ah[fr], bl_[fc], acc[fr][fc], 0, 0, 0);
        acc[fr][fc] = __builtin_amdgcn_mfma_f32_16x16x32_bf16(
            al_[fr], bh[fc], acc[fr][fc], 0, 0, 0);
      }
    buf ^= 1;
  }
  __syncthreads();   // all waves done with last tile before Et overwrites

  // ---- epilogue ----
  float (*Et)[132] = (float(*)[132])(smem);          // 64 rows x 132 (padded)
  float (*R2)[8]   = (float(*)[8])(smem + 33792);    // standard chains
  float (*R3)[8]   = (float(*)[8])(smem + 35840);    // mirror chains (128x8)

  float sj[4];
#pragma unroll
  for (int fc = 0; fc < 4; ++fc) sj[fc] = sqn32[j0 + wc * 64 + fc * 16 + lr];

  bool mir = (bx != by);

#pragma unroll
  for (int pass = 0; pass < 2; ++pass) {
    if (wr == pass) {
#pragma unroll
      for (int fr = 0; fr < 4; ++fr) {
#pragma unroll
        for (int v = 0; v < 4; ++v) {
          int irow = fr * 16 + lk * 4 + v;          // 0..63 within pass half
          int i = i0 + pass * 64 + irow;
          float si = sqn32[i];
#pragma unroll
          for (int fc = 0; fc < 4; ++fc) {
            int jcol = wc * 64 + fc * 16 + lr;
            int j = j0 + jcol;
            float sq = si + sj[fc] - 2.0f * acc[fr][fc][v];
            float e = (sq > 0.0f && i != j) ? sqrtf(sq) : 0.0f;
            Et[irow][jcol] = e;
            int q = (int)(e * 1024.0f + 0.5f);
            if (q > 65535) q = 65535;
            eud[(size_t)i * N + j] = (unsigned short)q;
          }
        }
      }
    }
    __syncthreads();

    // standard numpy leaf chains: 64 rows x 8 accs, stride-8 ascending
#pragma unroll
    for (int u0 = 0; u0 < 2; ++u0) {
      int u = tid + u0 * 256;                       // 0..511
      int row = u >> 3, m = u & 7;
      float s = Et[row][m];
#pragma unroll
      for (int g = 1; g < 16; ++g) s += Et[row][8 * g + m];
      R2[row][m] = s;
    }

    if (mir) {
      // mirror partial chains: leaf elem idx = 64*pass + 8g + m over Et cols
#pragma unroll
      for (int u0 = 0; u0 < 4; ++u0) {
        int u = tid + u0 * 256;                     // 0..1023
        int jofs = u >> 3, m = u & 7;
        float s = (pass == 0) ? 0.0f : R3[jofs][m];
#pragma unroll
        for (int g = 0; g < 8; ++g) s += Et[8 * g + m][jofs];
        R3[jofs][m] = s;
      }
      // mirror eud write: eud[j][i-range], re-quantized from same floats
      {
        int j = tid >> 1, h = tid & 1;
        size_t base2 = (size_t)(j0 + j) * N + i0 + pass * 64 + h * 32;
        unsigned short buf2[32];
#pragma unroll
        for (int ii = 0; ii < 32; ++ii) {
          float e = Et[h * 32 + ii][j];
          int q = (int)(e * 1024.0f + 0.5f);
          if (q > 65535) q = 65535;
          buf2[ii] = (unsigned short)q;
        }
#pragma unroll
        for (int q4 = 0; q4 < 4; ++q4)
          *(uint4*)(eud + base2 + q4 * 8) = *(uint4*)&buf2[q4 * 8];
      }
    }
    __syncthreads();

    if (tid < 64) {
      float v = ((R2[tid][0] + R2[tid][1]) + (R2[tid][2] + R2[tid][3])) +
                ((R2[tid][4] + R2[tid][5]) + (R2[tid][6] + R2[tid][7]));
      leaf[(size_t)(i0 + pass * 64 + tid) * 64 + bx] = v;
    }
    if (mir && pass == 1 && tid < 128) {
      float v = ((R3[tid][0] + R3[tid][1]) + (R3[tid][2] + R3[tid][3])) +
                ((R3[tid][4] + R3[tid][5]) + (R3[tid][6] + R3[tid][7]));
      leaf[(size_t)(j0 + tid) * 64 + by] = v;
    }
    __syncthreads();
  }
}

// ---- rowsel (r19): Sa + Se + tau-compact + rank-based top-16 --------------
// Score canonicalized via fbar in BOTH passes -> bitwise-equal values ->
// tau (16th-largest distinct of 256 thread maxima) guarantees C >= 16.
// Prefill makes every cand slot a valid index regardless (crash insurance).
#define CAP 640
__global__ __launch_bounds__(256) void knn_rowsel(
    const float* __restrict__ adj, const unsigned short* __restrict__ eud,
    const float* __restrict__ leaf, int* __restrict__ cand,
    float* __restrict__ cansc,
    float* __restrict__ SaOut, float* __restrict__ SeOut, int N) {
  __shared__ float arow[8192];
  __shared__ float R[64][8];
  __shared__ float Lf[64];
  __shared__ float bc[2];
  __shared__ int   cnt;
  __shared__ float ls[CAP];
  __shared__ int   lj[CAP];

  int row = blockIdx.x;
  int t = threadIdx.x;
  const float* ar = adj + (size_t)row * N;

  // stage adjacency row (32 KB) once
#pragma unroll
  for (int c = 0; c < 8; ++c)
    ((float4*)arow)[c * 256 + t] = ((const float4*)ar)[c * 256 + t];
  if (t == 0) cnt = 0;
  __syncthreads();

  // Sa: numpy pairwise order — 64 leaves of 128, 8 stride-8 accumulators
  for (int u = t; u < 512; u += 256) {
    int lf = u >> 3, m = u & 7;
    float s = arow[lf * 128 + m];
    for (int g = 1; g < 16; ++g) s += arow[lf * 128 + 8 * g + m];
    R[lf][m] = s;
  }
  __syncthreads();
  if (t < 64)
    Lf[t] = ((R[t][0] + R[t][1]) + (R[t][2] + R[t][3])) +
            ((R[t][4] + R[t][5]) + (R[t][6] + R[t][7]));
  __syncthreads();
  for (int w = 32; w >= 1; w >>= 1) {
    if (t < w) Lf[t] = Lf[2 * t] + Lf[2 * t + 1];
    __syncthreads();
  }
  if (t == 0) { float Sa = Lf[0]; SaOut[row] = Sa; bc[0] = 1.0f / Sa; }
  __syncthreads();

  // Se: balanced tree over the 64 numpy-ordered gemm leaf sums
  if (t < 64) Lf[t] = leaf[(size_t)row * 64 + t];
  __syncthreads();
  for (int w = 32; w >= 1; w >>= 1) {
    if (t < w) Lf[t] = Lf[2 * t] + Lf[2 * t + 1];
    __syncthreads();
  }
  if (t == 0) {
    float Se = Lf[0]; SeOut[row] = Se;
    bc[1] = (float)(1.0 / ((double)Se * 1024.0));
  }
  __syncthreads();
  float ra = bc[0], re = bc[1];

  const unsigned short* er = eud + (size_t)row * N;

  // canonical score: two pinned products + one add (identical both passes)
#define SCORE(avc, evc) (fbar((avc) * ra) + fbar((float)(evc) * re))

  // pass A: per-thread max of its 32 scores. maxv reuses R (float, dead).
  float* maxv = &R[0][0];
  float mx = -3.0e38f;
#pragma unroll
  for (int it = 0; it < 8; ++it) {
    int j = it * 1024 + t * 4;
    float4 av = *(const float4*)(arow + j);
    ushort4 ev = *(const ushort4*)(er + j);
    mx = fmaxf(mx, SCORE(av.x, ev.x));
    mx = fmaxf(mx, SCORE(av.y, ev.y));
    mx = fmaxf(mx, SCORE(av.z, ev.z));
    mx = fmaxf(mx, SCORE(av.w, ev.w));
  }
  maxv[t] = mx;
  __syncthreads();

  // tau: 16th-largest distinct of the 256 maxima — all waves redundantly
  float tau = -3.0e38f;
  {
    int lane = t & 63;
    float a0 = maxv[lane], a1 = maxv[lane + 64];
    float a2 = maxv[lane + 128], a3 = maxv[lane + 192];
#pragma unroll
    for (int r = 0; r < 16; ++r) {
      float cv = fmaxf(fmaxf(a0, a1), fmaxf(a2, a3));
      for (int off = 32; off; off >>= 1) cv = fmaxf(cv, __shfl_xor(cv, off));
      tau = cv;
      if (a0 == cv) a0 = -3.0e38f;
      if (a1 == cv) a1 = -3.0e38f;
      if (a2 == cv) a2 = -3.0e38f;
      if (a3 == cv) a3 = -3.0e38f;
    }
  }
  __syncthreads();

  // pass B: compact all (score, j) with score >= tau (identical SCORE)
#pragma unroll
  for (int it = 0; it < 8; ++it) {
    int j = it * 1024 + t * 4;
    float4 av = *(const float4*)(arow + j);
    ushort4 ev = *(const ushort4*)(er + j);
    float s0 = SCORE(av.x, ev.x);
    float s1 = SCORE(av.y, ev.y);
    float s2 = SCORE(av.z, ev.z);
    float s3 = SCORE(av.w, ev.w);
    if (s0 >= tau) { int p = atomicAdd(&cnt, 1); if (p < CAP) { ls[p] = s0; lj[p] = j + 0; } }
    if (s1 >= tau) { int p = atomicAdd(&cnt, 1); if (p < CAP) { ls[p] = s1; lj[p] = j + 1; } }
    if (s2 >= tau) { int p = atomicAdd(&cnt, 1); if (p < CAP) { ls[p] = s2; lj[p] = j + 2; } }
    if (s3 >= tau) { int p = atomicAdd(&cnt, 1); if (p < CAP) { ls[p] = s3; lj[p] = j + 3; } }
  }
#undef SCORE
  __syncthreads();
  int C = cnt < CAP ? cnt : CAP;

  // prefill ALL 64 slots: 0..15 valid small indices (crash insurance if a
  // rank were ever missed), 16..63 sentinels (rank >= 16 in refine).
  if (t < 64) {
    cand[(size_t)row * 64 + t] = (t < 16) ? t : (0x40000000 + t);
    cansc[(size_t)row * 64 + t] = -3.0e38f;
  }
  __syncthreads();   // prefill ordered before rank-pass overwrites

  // rank pass: element i's rank = #{k: (s_k,j_k) > (s_i,j_i)}; rank<16 wins.
  // Indices unique -> strict total order -> exactly one element per rank.
  for (int i = t; i < C; i += 256) {
    float si = ls[i]; int ji = lj[i];
    int rank = 0;
    for (int k = 0; k < C; ++k) {
      float vk = ls[k]; int jk = lj[k];
      if (vk > si || (vk == si && jk < ji)) ++rank;
    }
    if (rank < 16) {
      cand[(size_t)row * 64 + rank] = ji;
      cansc[(size_t)row * 64 + rank] = si;
    }
  }
}

// ---- phase 2 (r19): wave-cooperative exact re-score of approx-top-16 ------
// [4][136] LDS padding; gidx zero-init insurance; final top-9 via wave-0
// register shfl-argmax (exact same total order).
__global__ __launch_bounds__(256) void knn_refine(
    const float* __restrict__ f, const float* __restrict__ adj,
    const float* __restrict__ Sa, const float* __restrict__ Se,
    const int* __restrict__ cand, const float* __restrict__ cansc,
    float* __restrict__ out, int N, int D, int KP1) {
  int row = blockIdx.x;
  int t = threadIdx.x;
  int wave = t >> 6, lane = t & 63;

  __shared__ float fis[4][136];
  __shared__ float fjs[4][2][4][136];
  __shared__ float sval[64];
  __shared__ float asc[64];
  __shared__ int   ajx[64];
  __shared__ int   gidx[16];

  if (t < 64) {
    ajx[t] = cand[(size_t)row * 64 + t];
    asc[t] = cansc[(size_t)row * 64 + t];
    sval[t] = -3.0e38f;
  }
  if (t >= 64 && t < 80) gidx[t - 64] = 0;   // insurance: valid list pos
  if (t < 128) {
    int e0 = t * 4;
    *(float4*)&fis[e0 >> 7][e0 & 127] =
        ((const float4*)(f + (size_t)row * D))[t];
  }
  __syncthreads();

  // approx rank among the 64 (tie-break: lower index ranks higher)
  if (t < 64) {
    int myj = ajx[t]; float mys = asc[t];
    int rank = 0;
    for (int c = 0; c < 64; ++c) {
      float v = asc[c]; int jc = ajx[c];
      if (v > mys || (v == mys && jc < myj)) ++rank;
    }
    if (rank < 16) gidx[rank] = t;
  }
  __syncthreads();

  float sa = Sa[row], se = Se[row];
  int h = lane >> 5;        // half 0/1 within wave
  int hl = lane & 31;       // lane in half
  int lf = hl >> 3, m = hl & 7;

#pragma unroll
  for (int p = 0; p < 2; ++p) {
    int slot = wave * 4 + p * 2 + h;        // rank slot handled by this half
    int c = gidx[slot];
    int j = ajx[c];

    // stage fj: 32 lanes x 4 float4 = 2 KB, coalesced
    const float4* fj4 = (const float4*)(f + (size_t)j * D);
#pragma unroll
    for (int q = 0; q < 4; ++q) {
      int e0 = (hl * 4 + q) * 4;
      *(float4*)&fjs[wave][h][e0 >> 7][e0 & 127] = fj4[hl * 4 + q];
    }

    // chain (lf,m): acc over g=0..15 of fl((a-b)^2), ascending
    const float* ai = fis[lf];
    const float* bi = fjs[wave][h][lf];
    float d0 = ai[m] - bi[m];
    float acc = fbar(d0 * d0);
#pragma unroll
    for (int g = 1; g < 16; ++g) {
      float d = ai[8 * g + m] - bi[8 * g + m];
      acc = acc + fbar(d * d);
    }
    // m-tree: ((r0+r1)+(r2+r3))+((r4+r5)+(r6+r7))  [xor-butterfly, exact]
    float u = acc + __shfl_xor(acc, 1);
    u = u + __shfl_xor(u, 2);
    u = u + __shfl_xor(u, 4);
    // leaf tree: (L0+L1)+(L2+L3)
    float s1 = u + __shfl_xor(u, 8);
    float sq = s1 + __shfl_xor(s1, 16);

    if (hl == 0) {
      float e = sq > 0.0f ? (float)sqrt((double)sq) : 0.0f;
      sval[c] = adj[(size_t)row * N + j] / sa + e / se;
    }
  }
  __syncthreads();

  // wave-parallel top-9: lane c holds (sval[c], ajx[c]); 9 shfl-argmax
  // rounds with the exact comparator; winner removal by unique index.
  if (wave == 0) {
    float v = sval[lane];
    int j = ajx[lane];
    size_t NK = (size_t)N * KP1;
    size_t ob = (size_t)row * KP1;
    for (int r = 0; r < KP1; ++r) {
      float cv = v; int cj = j;
      for (int off = 32; off; off >>= 1) {
        float ov = __shfl_xor(cv, off);
        int oj = __shfl_xor(cj, off);
        if (ov > cv || (ov == cv && oj < cj)) { cv = ov; cj = oj; }
      }
      if (lane == 0) {
        out[ob + r]          = (float)row;  // edge_index row 0 (src)
        out[NK + ob + r]     = (float)cj;   // edge_index row 1 (dst)
        out[2 * NK + ob + r] = cv;          // edge_weights (faithful fp32)
      }
      if (j == cj) v = -2.0f;               // remove winner (j unique)
    }
  }
}

static inline size_t alignup(size_t x, size_t a) { return (x + a - 1) & ~(a - 1); }

extern "C" void kernel_launch(void* const* d_in, const int* in_sizes, int n_in,
                              void* d_out, int out_size, void* d_ws, size_t ws_size,
                              hipStream_t stream) {
  const float* f   = (const float*)d_in[0];
  const float* adj = (const float*)d_in[1];

  long long nn = in_sizes[1];
  int N = (int)llround(sqrt((double)nn));
  int D = in_sizes[0] / N;
  int KP1 = out_size / (3 * N);

  char* w = (char*)d_ws;
  size_t off = 0;
  float* sqn32 = (float*)(w + off); off = alignup(off + (size_t)N * 4, 256);
  float* Sa    = (float*)(w + off); off = alignup(off + (size_t)N * 4, 256);
  float* Se    = (float*)(w + off); off = alignup(off + (size_t)N * 4, 256);
  float* leaf  = (float*)(w + off); off = alignup(off + (size_t)N * 64 * 4, 256);
  int* cand    = (int*)(w + off);   off = alignup(off + (size_t)N * 64 * 4, 256);
  float* cansc = (float*)(w + off); off = alignup(off + (size_t)N * 64 * 4, 256);
  unsigned short* fhi = (unsigned short*)(w + off); off = alignup(off + (size_t)N * D * 2, 256);
  unsigned short* flo = (unsigned short*)(w + off); off = alignup(off + (size_t)N * D * 2, 256);
  unsigned short* eud = (unsigned short*)(w + off); off += (size_t)N * N * 2;
  (void)ws_size;

  int n4 = N * D / 4;
  int NT = N / TBM;
  int nblk = NT * (NT + 1) / 2;
  knn_cvt<<<(n4 + 255) / 256, 256, 0, stream>>>(f, fhi, flo, n4);
  knn_sqn_np<<<N, 128, 0, stream>>>(f, sqn32, N, D);
  knn_gemm_mfma<<<nblk, 256, 0, stream>>>(fhi, flo, sqn32, eud, leaf, N, D);
  knn_rowsel<<<N, 256, 0, stream>>>(adj, eud, leaf, cand, cansc, Sa, Se, N);
  knn_refine<<<N, 256, 0, stream>>>(f, adj, Sa, Se, cand, cansc,
                                    (float*)d_out, N, D, KP1);
}

// Round 22
// 393.113 us; speedup vs baseline: 1.3191x; 1.0051x over previous
//
#include <hip/hip_runtime.h>
#include <hip/hip_bf16.h>
#include <math.h>

// ---------------------------------------------------------------------------
// Hypergraph kNN, fp32-faithful to a numpy float32 reference:
//   eud[i,j] = sqrt( np.sum( (f[i]-f[j])**2 ) )   (DIRECT form, verified r6)
//   distances = adj/np.sum(adj,1) + eud/np.sum(eud,1);  top-9 per row.
// Phase 1: split-bf16 MFMA GEMM (triangular, 2-phase dbuf global_load_lds
//   staging, XOR k-block swizzle) -> u16 eud + numpy-ordered fp32 leaf sums.
//   r22: bijective XCD-aware block swizzle (nblk=2080 % 8 == 0 -> exact
//   chunked mapping) — contiguous triangular blocks per XCD share A-row
//   panels in that XCD's private L2. Pure reordering; output bit-identical.
// rowsel (r19): Sa + Se + fbar-canonical tau-compact top-16 (C>=16 proof).
// Phase 2: wave-cooperative exact re-score of approx-top-16 (r13/r15/r19).
// ---------------------------------------------------------------------------

typedef short bf16x8 __attribute__((ext_vector_type(8)));   // 8 bf16 (4 VGPR)
typedef float f32x4 __attribute__((ext_vector_type(4)));

__device__ __forceinline__ float fbar(float x) {  // pin value; block contract
  asm volatile("" : "+v"(x));
  return x;
}
__device__ __forceinline__ unsigned short f2bf(float x) {  // RNE
  union { float f; unsigned u; } v; v.f = x;
  unsigned r = (v.u + 0x7fffu + ((v.u >> 16) & 1u)) >> 16;
  return (unsigned short)r;
}
__device__ __forceinline__ float bf2f(unsigned short b) {
  union { unsigned u; float f; } v; v.u = ((unsigned)b) << 16; return v.f;
}
__device__ __forceinline__ void gload_lds16(const void* g, void* l) {
  __builtin_amdgcn_global_load_lds(
      (const __attribute__((address_space(1))) unsigned int*)g,
      (__attribute__((address_space(3))) unsigned int*)l, 16, 0, 0);
}

// ---- split f32 -> hi/lo bf16 planes ---------------------------------------
__global__ __launch_bounds__(256) void knn_cvt(const float* __restrict__ f,
                                               unsigned short* __restrict__ hi,
                                               unsigned short* __restrict__ lo,
                                               int n4) {
  int i = blockIdx.x * 256 + threadIdx.x;
  if (i >= n4) return;
  float4 v = ((const float4*)f)[i];
  ushort4 h, l;
  h.x = f2bf(v.x); l.x = f2bf(v.x - bf2f(h.x));
  h.y = f2bf(v.y); l.y = f2bf(v.y - bf2f(h.y));
  h.z = f2bf(v.z); l.z = f2bf(v.z - bf2f(h.z));
  h.w = f2bf(v.w); l.w = f2bf(v.w - bf2f(h.w));
  ((ushort4*)hi)[i] = h;
  ((ushort4*)lo)[i] = l;
}

// ---- sq_norms: np.sum(f*f, axis=1) in exact numpy fp32 pairwise order -----
__global__ __launch_bounds__(128) void knn_sqn_np(const float* __restrict__ f,
                                                  float* __restrict__ sqn32,
                                                  int N, int D) {
  int row = blockIdx.x;             // D == 512: 4 leaves of 128
  int t = threadIdx.x;              // 128 threads
  __shared__ float a[512];
  __shared__ float R[4][8];
  const float* fr = f + (size_t)row * D;
  float4 v = ((const float4*)fr)[t];
  a[t * 4 + 0] = v.x * v.x;
  a[t * 4 + 1] = v.y * v.y;
  a[t * 4 + 2] = v.z * v.z;
  a[t * 4 + 3] = v.w * v.w;
  __syncthreads();
  if (t < 32) {
    int lf = t >> 3, m = t & 7;
    float s = a[lf * 128 + m];
    for (int g = 1; g < 16; ++g) s += a[lf * 128 + 8 * g + m];
    R[lf][m] = s;
  }
  __syncthreads();
  if (t == 0) {
    float L[4];
#pragma unroll
    for (int lf = 0; lf < 4; ++lf)
      L[lf] = ((R[lf][0] + R[lf][1]) + (R[lf][2] + R[lf][3])) +
              ((R[lf][4] + R[lf][5]) + (R[lf][6] + R[lf][7]));
    sqn32[row] = (L[0] + L[1]) + (L[2] + L[3]);
  }
}

// ---- split-bf16 MFMA GEMM: 128x128 tile, 4 waves, BK=32, TRIANGULAR -------
// 2-phase double-buffered staging; one barrier/iter. Physical 16B block p of
// row r holds logical k-block (p ^ (r&3)). r22: XCD-chunked block swizzle.
#define TBM 128
#define TBN 128
#define TBK 32
__global__ __launch_bounds__(256) void knn_gemm_mfma(
    const unsigned short* __restrict__ fhi, const unsigned short* __restrict__ flo,
    const float* __restrict__ sqn32, unsigned short* __restrict__ eud,
    float* __restrict__ leaf, int N, int D) {
  // LDS: 2 staging buffers (32768 B each); epilogue aliases the first 40 KB:
  // Et[64][132] (33792) + R2[64][8] (@33792) + R3[128][8] (@35840)
  __shared__ __align__(16) char smem[65536];

  int tid = threadIdx.x;

  // XCD-aware bijective swizzle (valid when nblk % 8 == 0; else identity):
  // XCD k gets contiguous triangular blocks [k*nblk/8, (k+1)*nblk/8).
  int nblk = gridDim.x;
  int b = blockIdx.x;
  if ((nblk & 7) == 0) b = (b & 7) * (nblk >> 3) + (b >> 3);

  // triangular decode: block -> (by <= bx)
  int NT = N / TBM;
  int by = 0, rem = NT;
  while (b >= rem) { b -= rem; ++by; --rem; }
  int bx = by + b;

  int i0 = by * TBM, j0 = bx * TBN;
  int wid = tid >> 6, l = tid & 63;
  int wr = wid >> 1, wc = wid & 1;  // wave -> 64x64 quadrant
  int lr = l & 15, lk = l >> 4;     // frag row, k-chunk

  f32x4 acc[4][4] = {};             // statically indexed only (unrolled)

  // staging geometry (wave wid stages array wid: Ah, Al, Bh, Bl)
  const unsigned short* gp = (wid & 1) ? flo : fhi;
  int rbase = (wid < 2) ? i0 : j0;
  int lrow = l >> 2;                // 0..15
  int lblk = l & 3;                 // physical 16B block within row
  int kblk = lblk ^ (lrow & 3);     // logical k-block this lane fetches

  // prologue: stage tile k0=0 into buffer 0
  {
    unsigned short* Lp = (unsigned short*)(smem + wid * 8192);
#pragma unroll
    for (int i = 0; i < 8; ++i) {
      int r = i * 16 + lrow;
      const unsigned short* g = gp + (size_t)(rbase + r) * D + kblk * 8;
      gload_lds16(g, Lp + (size_t)r * 32 + lblk * 8);
    }
  }

  int buf = 0;
  for (int k0 = 0; k0 < D; k0 += TBK) {
    __syncthreads();   // implicit vmcnt(0): stage for current buffer drained

    // issue next tile's stage into the other buffer (flies under MFMA)
    if (k0 + TBK < D) {
      unsigned short* Lp = (unsigned short*)(smem + (buf ^ 1) * 32768 + wid * 8192);
#pragma unroll
      for (int i = 0; i < 8; ++i) {
        int r = i * 16 + lrow;
        const unsigned short* g =
            gp + (size_t)(rbase + r) * D + (k0 + TBK) + kblk * 8;
        gload_lds16(g, Lp + (size_t)r * 32 + lblk * 8);
      }
    }

    const char* base = smem + buf * 32768;
    const unsigned short* A_h = (const unsigned short*)(base);
    const unsigned short* A_l = (const unsigned short*)(base + 8192);
    const unsigned short* B_h = (const unsigned short*)(base + 16384);
    const unsigned short* B_l = (const unsigned short*)(base + 24576);

    bf16x8 ah[4], al_[4], bh[4], bl_[4];
#pragma unroll
    for (int fr = 0; fr < 4; ++fr) {
      int ra = wr * 64 + fr * 16 + lr;
      int rb = wc * 64 + fr * 16 + lr;
      int ka = (lk ^ (ra & 3)) * 8;
      int kb = (lk ^ (rb & 3)) * 8;
      ah[fr]  = *(const bf16x8*)(A_h + (size_t)ra * 32 + ka);
      al_[fr] = *(const bf16x8*)(A_l + (size_t)ra * 32 + ka);
      bh[fr]  = *(const bf16x8*)(B_h + (size_t)rb * 32 + kb);
      bl_[fr] = *(const bf16x8*)(B_l + (size_t)rb * 32 + kb);
    }
#pragma unroll
    for (int fr = 0; fr < 4; ++fr)
#pragma unroll
      for (int fc = 0; fc < 4; ++fc) {
        acc[fr][fc] = __builtin_amdgcn_mfma_f32_16x16x32_bf16(
            ah[fr], bh[fc], acc[fr][fc], 0, 0, 0);
        acc[fr][fc] = __builtin_amdgcn_mfma_f32_16x16x32_bf16(
            ah[fr], bl_[fc], acc[fr][fc], 0, 0, 0);
        acc[fr][fc] = __builtin_amdgcn_mfma_f32_16x16x32_bf16(
            al_[fr], bh[fc], acc[fr][fc], 0, 0, 0);
      }
    buf ^= 1;
  }
  __syncthreads();   // all waves done with last tile before Et overwrites

  // ---- epilogue ----
  float (*Et)[132] = (float(*)[132])(smem);          // 64 rows x 132 (padded)
  float (*R2)[8]   = (float(*)[8])(smem + 33792);    // standard chains
  float (*R3)[8]   = (float(*)[8])(smem + 35840);    // mirror chains (128x8)

  float sj[4];
#pragma unroll
  for (int fc = 0; fc < 4; ++fc) sj[fc] = sqn32[j0 + wc * 64 + fc * 16 + lr];

  bool mir = (bx != by);

#pragma unroll
  for (int pass = 0; pass < 2; ++pass) {
    if (wr == pass) {
#pragma unroll
      for (int fr = 0; fr < 4; ++fr) {
#pragma unroll
        for (int v = 0; v < 4; ++v) {
          int irow = fr * 16 + lk * 4 + v;          // 0..63 within pass half
          int i = i0 + pass * 64 + irow;
          float si = sqn32[i];
#pragma unroll
          for (int fc = 0; fc < 4; ++fc) {
            int jcol = wc * 64 + fc * 16 + lr;
            int j = j0 + jcol;
            float sq = si + sj[fc] - 2.0f * acc[fr][fc][v];
            float e = (sq > 0.0f && i != j) ? sqrtf(sq) : 0.0f;
            Et[irow][jcol] = e;
            int q = (int)(e * 1024.0f + 0.5f);
            if (q > 65535) q = 65535;
            eud[(size_t)i * N + j] = (unsigned short)q;
          }
        }
      }
    }
    __syncthreads();

    // standard numpy leaf chains: 64 rows x 8 accs, stride-8 ascending
#pragma unroll
    for (int u0 = 0; u0 < 2; ++u0) {
      int u = tid + u0 * 256;                       // 0..511
      int row = u >> 3, m = u & 7;
      float s = Et[row][m];
#pragma unroll
      for (int g = 1; g < 16; ++g) s += Et[row][8 * g + m];
      R2[row][m] = s;
    }

    if (mir) {
      // mirror partial chains: leaf elem idx = 64*pass + 8g + m over Et cols
#pragma unroll
      for (int u0 = 0; u0 < 4; ++u0) {
        int u = tid + u0 * 256;                     // 0..1023
        int jofs = u >> 3, m = u & 7;
        float s = (pass == 0) ? 0.0f : R3[jofs][m];
#pragma unroll
        for (int g = 0; g < 8; ++g) s += Et[8 * g + m][jofs];
        R3[jofs][m] = s;
      }
      // mirror eud write: eud[j][i-range], re-quantized from same floats
      {
        int j = tid >> 1, h = tid & 1;
        size_t base2 = (size_t)(j0 + j) * N + i0 + pass * 64 + h * 32;
        unsigned short buf2[32];
#pragma unroll
        for (int ii = 0; ii < 32; ++ii) {
          float e = Et[h * 32 + ii][j];
          int q = (int)(e * 1024.0f + 0.5f);
          if (q > 65535) q = 65535;
          buf2[ii] = (unsigned short)q;
        }
#pragma unroll
        for (int q4 = 0; q4 < 4; ++q4)
          *(uint4*)(eud + base2 + q4 * 8) = *(uint4*)&buf2[q4 * 8];
      }
    }
    __syncthreads();

    if (tid < 64) {
      float v = ((R2[tid][0] + R2[tid][1]) + (R2[tid][2] + R2[tid][3])) +
                ((R2[tid][4] + R2[tid][5]) + (R2[tid][6] + R2[tid][7]));
      leaf[(size_t)(i0 + pass * 64 + tid) * 64 + bx] = v;
    }
    if (mir && pass == 1 && tid < 128) {
      float v = ((R3[tid][0] + R3[tid][1]) + (R3[tid][2] + R3[tid][3])) +
                ((R3[tid][4] + R3[tid][5]) + (R3[tid][6] + R3[tid][7]));
      leaf[(size_t)(j0 + tid) * 64 + by] = v;
    }
    __syncthreads();
  }
}

// ---- rowsel (r19): Sa + Se + tau-compact + rank-based top-16 --------------
// Score canonicalized via fbar in BOTH passes -> bitwise-equal values ->
// tau (16th-largest distinct of 256 thread maxima) guarantees C >= 16.
// Prefill makes every cand slot a valid index regardless (crash insurance).
#define CAP 640
__global__ __launch_bounds__(256) void knn_rowsel(
    const float* __restrict__ adj, const unsigned short* __restrict__ eud,
    const float* __restrict__ leaf, int* __restrict__ cand,
    float* __restrict__ cansc,
    float* __restrict__ SaOut, float* __restrict__ SeOut, int N) {
  __shared__ float arow[8192];
  __shared__ float R[64][8];
  __shared__ float Lf[64];
  __shared__ float bc[2];
  __shared__ int   cnt;
  __shared__ float ls[CAP];
  __shared__ int   lj[CAP];

  int row = blockIdx.x;
  int t = threadIdx.x;
  const float* ar = adj + (size_t)row * N;

  // stage adjacency row (32 KB) once
#pragma unroll
  for (int c = 0; c < 8; ++c)
    ((float4*)arow)[c * 256 + t] = ((const float4*)ar)[c * 256 + t];
  if (t == 0) cnt = 0;
  __syncthreads();

  // Sa: numpy pairwise order — 64 leaves of 128, 8 stride-8 accumulators
  for (int u = t; u < 512; u += 256) {
    int lf = u >> 3, m = u & 7;
    float s = arow[lf * 128 + m];
    for (int g = 1; g < 16; ++g) s += arow[lf * 128 + 8 * g + m];
    R[lf][m] = s;
  }
  __syncthreads();
  if (t < 64)
    Lf[t] = ((R[t][0] + R[t][1]) + (R[t][2] + R[t][3])) +
            ((R[t][4] + R[t][5]) + (R[t][6] + R[t][7]));
  __syncthreads();
  for (int w = 32; w >= 1; w >>= 1) {
    if (t < w) Lf[t] = Lf[2 * t] + Lf[2 * t + 1];
    __syncthreads();
  }
  if (t == 0) { float Sa = Lf[0]; SaOut[row] = Sa; bc[0] = 1.0f / Sa; }
  __syncthreads();

  // Se: balanced tree over the 64 numpy-ordered gemm leaf sums
  if (t < 64) Lf[t] = leaf[(size_t)row * 64 + t];
  __syncthreads();
  for (int w = 32; w >= 1; w >>= 1) {
    if (t < w) Lf[t] = Lf[2 * t] + Lf[2 * t + 1];
    __syncthreads();
  }
  if (t == 0) {
    float Se = Lf[0]; SeOut[row] = Se;
    bc[1] = (float)(1.0 / ((double)Se * 1024.0));
  }
  __syncthreads();
  float ra = bc[0], re = bc[1];

  const unsigned short* er = eud + (size_t)row * N;

  // canonical score: two pinned products + one add (identical both passes)
#define SCORE(avc, evc) (fbar((avc) * ra) + fbar((float)(evc) * re))

  // pass A: per-thread max of its 32 scores. maxv reuses R (float, dead).
  float* maxv = &R[0][0];
  float mx = -3.0e38f;
#pragma unroll
  for (int it = 0; it < 8; ++it) {
    int j = it * 1024 + t * 4;
    float4 av = *(const float4*)(arow + j);
    ushort4 ev = *(const ushort4*)(er + j);
    mx = fmaxf(mx, SCORE(av.x, ev.x));
    mx = fmaxf(mx, SCORE(av.y, ev.y));
    mx = fmaxf(mx, SCORE(av.z, ev.z));
    mx = fmaxf(mx, SCORE(av.w, ev.w));
  }
  maxv[t] = mx;
  __syncthreads();

  // tau: 16th-largest distinct of the 256 maxima — all waves redundantly
  float tau = -3.0e38f;
  {
    int lane = t & 63;
    float a0 = maxv[lane], a1 = maxv[lane + 64];
    float a2 = maxv[lane + 128], a3 = maxv[lane + 192];
#pragma unroll
    for (int r = 0; r < 16; ++r) {
      float cv = fmaxf(fmaxf(a0, a1), fmaxf(a2, a3));
      for (int off = 32; off; off >>= 1) cv = fmaxf(cv, __shfl_xor(cv, off));
      tau = cv;
      if (a0 == cv) a0 = -3.0e38f;
      if (a1 == cv) a1 = -3.0e38f;
      if (a2 == cv) a2 = -3.0e38f;
      if (a3 == cv) a3 = -3.0e38f;
    }
  }
  __syncthreads();

  // pass B: compact all (score, j) with score >= tau (identical SCORE)
#pragma unroll
  for (int it = 0; it < 8; ++it) {
    int j = it * 1024 + t * 4;
    float4 av = *(const float4*)(arow + j);
    ushort4 ev = *(const ushort4*)(er + j);
    float s0 = SCORE(av.x, ev.x);
    float s1 = SCORE(av.y, ev.y);
    float s2 = SCORE(av.z, ev.z);
    float s3 = SCORE(av.w, ev.w);
    if (s0 >= tau) { int p = atomicAdd(&cnt, 1); if (p < CAP) { ls[p] = s0; lj[p] = j + 0; } }
    if (s1 >= tau) { int p = atomicAdd(&cnt, 1); if (p < CAP) { ls[p] = s1; lj[p] = j + 1; } }
    if (s2 >= tau) { int p = atomicAdd(&cnt, 1); if (p < CAP) { ls[p] = s2; lj[p] = j + 2; } }
    if (s3 >= tau) { int p = atomicAdd(&cnt, 1); if (p < CAP) { ls[p] = s3; lj[p] = j + 3; } }
  }
#undef SCORE
  __syncthreads();
  int C = cnt < CAP ? cnt : CAP;

  // prefill ALL 64 slots: 0..15 valid small indices (crash insurance if a
  // rank were ever missed), 16..63 sentinels (rank >= 16 in refine).
  if (t < 64) {
    cand[(size_t)row * 64 + t] = (t < 16) ? t : (0x40000000 + t);
    cansc[(size_t)row * 64 + t] = -3.0e38f;
  }
  __syncthreads();   // prefill ordered before rank-pass overwrites

  // rank pass: element i's rank = #{k: (s_k,j_k) > (s_i,j_i)}; rank<16 wins.
  // Indices unique -> strict total order -> exactly one element per rank.
  for (int i = t; i < C; i += 256) {
    float si = ls[i]; int ji = lj[i];
    int rank = 0;
    for (int k = 0; k < C; ++k) {
      float vk = ls[k]; int jk = lj[k];
      if (vk > si || (vk == si && jk < ji)) ++rank;
    }
    if (rank < 16) {
      cand[(size_t)row * 64 + rank] = ji;
      cansc[(size_t)row * 64 + rank] = si;
    }
  }
}

// ---- phase 2 (r19): wave-cooperative exact re-score of approx-top-16 ------
// [4][136] LDS padding; gidx zero-init insurance; final top-9 via wave-0
// register shfl-argmax (exact same total order).
__global__ __launch_bounds__(256) void knn_refine(
    const float* __restrict__ f, const float* __restrict__ adj,
    const float* __restrict__ Sa, const float* __restrict__ Se,
    const int* __restrict__ cand, const float* __restrict__ cansc,
    float* __restrict__ out, int N, int D, int KP1) {
  int row = blockIdx.x;
  int t = threadIdx.x;
  int wave = t >> 6, lane = t & 63;

  __shared__ float fis[4][136];
  __shared__ float fjs[4][2][4][136];
  __shared__ float sval[64];
  __shared__ float asc[64];
  __shared__ int   ajx[64];
  __shared__ int   gidx[16];

  if (t < 64) {
    ajx[t] = cand[(size_t)row * 64 + t];
    asc[t] = cansc[(size_t)row * 64 + t];
    sval[t] = -3.0e38f;
  }
  if (t >= 64 && t < 80) gidx[t - 64] = 0;   // insurance: valid list pos
  if (t < 128) {
    int e0 = t * 4;
    *(float4*)&fis[e0 >> 7][e0 & 127] =
        ((const float4*)(f + (size_t)row * D))[t];
  }
  __syncthreads();

  // approx rank among the 64 (tie-break: lower index ranks higher)
  if (t < 64) {
    int myj = ajx[t]; float mys = asc[t];
    int rank = 0;
    for (int c = 0; c < 64; ++c) {
      float v = asc[c]; int jc = ajx[c];
      if (v > mys || (v == mys && jc < myj)) ++rank;
    }
    if (rank < 16) gidx[rank] = t;
  }
  __syncthreads();

  float sa = Sa[row], se = Se[row];
  int h = lane >> 5;        // half 0/1 within wave
  int hl = lane & 31;       // lane in half
  int lf = hl >> 3, m = hl & 7;

#pragma unroll
  for (int p = 0; p < 2; ++p) {
    int slot = wave * 4 + p * 2 + h;        // rank slot handled by this half
    int c = gidx[slot];
    int j = ajx[c];

    // stage fj: 32 lanes x 4 float4 = 2 KB, coalesced
    const float4* fj4 = (const float4*)(f + (size_t)j * D);
#pragma unroll
    for (int q = 0; q < 4; ++q) {
      int e0 = (hl * 4 + q) * 4;
      *(float4*)&fjs[wave][h][e0 >> 7][e0 & 127] = fj4[hl * 4 + q];
    }

    // chain (lf,m): acc over g=0..15 of fl((a-b)^2), ascending
    const float* ai = fis[lf];
    const float* bi = fjs[wave][h][lf];
    float d0 = ai[m] - bi[m];
    float acc = fbar(d0 * d0);
#pragma unroll
    for (int g = 1; g < 16; ++g) {
      float d = ai[8 * g + m] - bi[8 * g + m];
      acc = acc + fbar(d * d);
    }
    // m-tree: ((r0+r1)+(r2+r3))+((r4+r5)+(r6+r7))  [xor-butterfly, exact]
    float u = acc + __shfl_xor(acc, 1);
    u = u + __shfl_xor(u, 2);
    u = u + __shfl_xor(u, 4);
    // leaf tree: (L0+L1)+(L2+L3)
    float s1 = u + __shfl_xor(u, 8);
    float sq = s1 + __shfl_xor(s1, 16);

    if (hl == 0) {
      float e = sq > 0.0f ? (float)sqrt((double)sq) : 0.0f;
      sval[c] = adj[(size_t)row * N + j] / sa + e / se;
    }
  }
  __syncthreads();

  // wave-parallel top-9: lane c holds (sval[c], ajx[c]); 9 shfl-argmax
  // rounds with the exact comparator; winner removal by unique index.
  if (wave == 0) {
    float v = sval[lane];
    int j = ajx[lane];
    size_t NK = (size_t)N * KP1;
    size_t ob = (size_t)row * KP1;
    for (int r = 0; r < KP1; ++r) {
      float cv = v; int cj = j;
      for (int off = 32; off; off >>= 1) {
        float ov = __shfl_xor(cv, off);
        int oj = __shfl_xor(cj, off);
        if (ov > cv || (ov == cv && oj < cj)) { cv = ov; cj = oj; }
      }
      if (lane == 0) {
        out[ob + r]          = (float)row;  // edge_index row 0 (src)
        out[NK + ob + r]     = (float)cj;   // edge_index row 1 (dst)
        out[2 * NK + ob + r] = cv;          // edge_weights (faithful fp32)
      }
      if (j == cj) v = -2.0f;               // remove winner (j unique)
    }
  }
}

static inline size_t alignup(size_t x, size_t a) { return (x + a - 1) & ~(a - 1); }

extern "C" void kernel_launch(void* const* d_in, const int* in_sizes, int n_in,
                              void* d_out, int out_size, void* d_ws, size_t ws_size,
                              hipStream_t stream) {
  const float* f   = (const float*)d_in[0];
  const float* adj = (const float*)d_in[1];

  long long nn = in_sizes[1];
  int N = (int)llround(sqrt((double)nn));
  int D = in_sizes[0] / N;
  int KP1 = out_size / (3 * N);

  char* w = (char*)d_ws;
  size_t off = 0;
  float* sqn32 = (float*)(w + off); off = alignup(off + (size_t)N * 4, 256);
  float* Sa    = (float*)(w + off); off = alignup(off + (size_t)N * 4, 256);
  float* Se    = (float*)(w + off); off = alignup(off + (size_t)N * 4, 256);
  float* leaf  = (float*)(w + off); off = alignup(off + (size_t)N * 64 * 4, 256);
  int* cand    = (int*)(w + off);   off = alignup(off + (size_t)N * 64 * 4, 256);
  float* cansc = (float*)(w + off); off = alignup(off + (size_t)N * 64 * 4, 256);
  unsigned short* fhi = (unsigned short*)(w + off); off = alignup(off + (size_t)N * D * 2, 256);
  unsigned short* flo = (unsigned short*)(w + off); off = alignup(off + (size_t)N * D * 2, 256);
  unsigned short* eud = (unsigned short*)(w + off); off += (size_t)N * N * 2;
  (void)ws_size;

  int n4 = N * D / 4;
  int NT = N / TBM;
  int nblk = NT * (NT + 1) / 2;
  knn_cvt<<<(n4 + 255) / 256, 256, 0, stream>>>(f, fhi, flo, n4);
  knn_sqn_np<<<N, 128, 0, stream>>>(f, sqn32, N, D);
  knn_gemm_mfma<<<nblk, 256, 0, stream>>>(fhi, flo, sqn32, eud, leaf, N, D);
  knn_rowsel<<<N, 256, 0, stream>>>(adj, eud, leaf, cand, cansc, Sa, Se, N);
  knn_refine<<<N, 256, 0, stream>>>(f, adj, Sa, Se, cand, cansc,
                                    (float*)d_out, N, D, KP1);
}